// Round 9
// baseline (449.885 us; speedup 1.0000x reference)
//
#include <hip/hip_runtime.h>
#include <math.h>

#define BQ 64
#define HH 128
#define EPS 1e-8f

typedef short bf16x8 __attribute__((ext_vector_type(8)));
typedef float f32x4  __attribute__((ext_vector_type(4)));

__device__ __forceinline__ float gelu_exact(float x) {
    return 0.5f * x * (1.0f + erff(x * 0.70710678118654752440f));
}

// round-to-nearest-even fp32 -> bf16 (returned in low 16 bits)
__device__ __forceinline__ unsigned bf16_rne(float x) {
    unsigned u = __float_as_uint(x);
    return (u + 0x7FFFu + ((u >> 16) & 1u)) >> 16;
}
// split two floats into packed bf16 hi-plane and lo-plane words
__device__ __forceinline__ uint2 split_pack(float a, float b) {
    unsigned ha = bf16_rne(a);
    float fa = __uint_as_float(ha << 16);
    unsigned la = bf16_rne(a - fa);
    unsigned hb = bf16_rne(b);
    float fb = __uint_as_float(hb << 16);
    unsigned lb = bf16_rne(b - fb);
    uint2 r; r.x = ha | (hb << 16); r.y = la | (lb << 16);
    return r;
}

// ---------------------------------------------------------------------------
// FiLM projection (unchanged from r8)
// ---------------------------------------------------------------------------
__global__ __launch_bounds__(256)
void film2_kernel(const float* __restrict__ qe,
                  const float* __restrict__ fw0, const float* __restrict__ fb0,
                  const float* __restrict__ fw1, const float* __restrict__ fb1,
                  const float* __restrict__ fw2, const float* __restrict__ fb2,
                  float* __restrict__ gb0, float* __restrict__ gb1, float* __restrict__ gb2)
{
    __shared__ float sq[768];
    __shared__ float sP[256];
    const int tid = threadIdx.x, bq = blockIdx.x, chunk = blockIdx.y;
    int s, o0;
    if (chunk == 0)      { s = 0; o0 = 0; }
    else if (chunk <= 2) { s = 1; o0 = (chunk - 1) * 128; }
    else                 { s = 2; o0 = (chunk - 3) * 128; }
    const float* fw  = s == 0 ? fw0 : s == 1 ? fw1 : fw2;
    const float* fbv = s == 0 ? fb0 : s == 1 ? fb1 : fb2;
    float* gb        = s == 0 ? gb0 : s == 1 ? gb1 : gb2;
    const int twoC = 128 << s;

    for (int i = tid; i < 768; i += 256) sq[i] = qe[bq * 768 + i];
    __syncthreads();

    const int o = o0 + (tid & 127), half = tid >> 7;
    const int e0 = half * 384;
    float a0 = 0.f, a1 = 0.f;
    #pragma unroll 2
    for (int e = 0; e < 384; e += 2) {
        a0 = fmaf(sq[e0 + e],     fw[(e0 + e) * twoC + o],     a0);
        a1 = fmaf(sq[e0 + e + 1], fw[(e0 + e + 1) * twoC + o], a1);
    }
    sP[tid] = a0 + a1;
    __syncthreads();
    if (tid < 128) {
        int oo = o0 + tid;
        gb[bq * twoC + oo] = sP[tid] + sP[tid + 128] + fbv[oo];
    }
}

// ---------------------------------------------------------------------------
// b2[bq, j] = hid_b[j] + sum_c beta[c] * hid_w[c, j]  (unchanged)
// ---------------------------------------------------------------------------
__global__ __launch_bounds__(256)
void b2_kernel(const float* __restrict__ gb0, const float* __restrict__ gb1,
               const float* __restrict__ gb2,
               const float* __restrict__ hw0_, const float* __restrict__ hb0,
               const float* __restrict__ hw1_, const float* __restrict__ hb1,
               const float* __restrict__ hw2_, const float* __restrict__ hb2,
               float* __restrict__ b20, float* __restrict__ b21, float* __restrict__ b22)
{
    __shared__ float sBeta[256];
    __shared__ float sP[256];
    const int tid = threadIdx.x, bq = blockIdx.x, s = blockIdx.y;
    const float* gb = s == 0 ? gb0 : s == 1 ? gb1 : gb2;
    const float* hw = s == 0 ? hw0_ : s == 1 ? hw1_ : hw2_;
    const float* hb = s == 0 ? hb0 : s == 1 ? hb1 : hb2;
    float* b2       = s == 0 ? b20 : s == 1 ? b21 : b22;
    const int C = 64 << s;

    for (int i = tid; i < C; i += 256) sBeta[i] = gb[bq * 2 * C + C + i];
    __syncthreads();
    const int j = tid & 127, half = tid >> 7;
    const int c0 = half * (C / 2);
    float acc = 0.f;
    for (int c = 0; c < C / 2; ++c)
        acc = fmaf(sBeta[c0 + c], hw[(c0 + c) * HH + j], acc);
    sP[tid] = acc;
    __syncthreads();
    if (tid < 128) b2[bq * HH + tid] = hb[tid] + sP[tid] + sP[tid + 128];
}

// ---------------------------------------------------------------------------
// MFMA FiLM pool. Block = 4 waves (256 thr), 64-px tile.
// D[px,j] = sum_c f[c,px] * (gamma[c]*W[c,j]) via mfma_f32_16x16x32_bf16
// with bf16 hi/lo split of BOTH operands (3 MFMA terms; lo*lo dropped ~2^-18).
// A = f tile [64px][32c], B = gammaW [128j][32c], both LDS-staged per K-step,
// rows padded to 40 bf16 (80 B) for bank spread; b128 frag reads.
// Wave w: A rows px = w*16+(lane&15); D: px = w*16+(lane>>4)*4+reg, j = jt*16+(lane&15).
// ---------------------------------------------------------------------------
template<int C, bool WRITE_ATTN>
__device__ __forceinline__
void pool_body(const float* __restrict__ feat, int HW,
               const float* __restrict__ gb, const float* __restrict__ b2,
               const float* __restrict__ hidw, const float* __restrict__ finw,
               const float* __restrict__ finb,
               float* __restrict__ Sout, float* __restrict__ attn_out,
               int bq, int tile,
               unsigned* sA, unsigned* sB, float* sAttn)
{
    const int tid  = threadIdx.x;
    const int w    = tid >> 6;
    const int lane = tid & 63;
    const int b    = bq >> 5;
    const int px0  = tile * 64;
    const float* fbase = feat + (size_t)b * C * HW;
    const float* g     = gb + bq * 2 * C;        // gamma at [0,C)

    f32x4 acc[8];
    #pragma unroll
    for (int jt = 0; jt < 8; ++jt) {
        float bv = b2[bq * HH + jt * 16 + (lane & 15)];
        acc[jt] = (f32x4){bv, bv, bv, bv};
    }

    // staging thread mapping
    const int spx = tid & 63;       // A: px row
    const int scq = tid >> 6;       // A: 0..3 pair phase
    const int sj  = tid & 127;      // B: j row
    const int sph = tid >> 7;       // B: 0..1 pair phase
    const int gpx = min(px0 + spx, HW - 1);

    const int arow = w * 16 + (lane & 15);
    const int koff = lane >> 4;     // k-slot: 4 u32 (8 bf16) per slot

    for (int ks = 0; ks < C / 32; ++ks) {
        const int c0 = ks * 32;
        // --- stage A: f tile [64px][32c] hi/lo (pairs of c packed per u32)
        #pragma unroll
        for (int i = 0; i < 4; ++i) {
            int p = scq + 4 * i;                 // pair 0..15
            int c = c0 + 2 * p;
            float fa = fbase[(size_t)c * HW + gpx];
            float fb = fbase[(size_t)(c + 1) * HW + gpx];
            uint2 hl = split_pack(fa, fb);
            sA[spx * 20 + p]        = hl.x;      // hi plane
            sA[1280 + spx * 20 + p] = hl.y;      // lo plane
        }
        // --- stage B: gammaW [128j][32c] hi/lo
        #pragma unroll
        for (int i = 0; i < 8; ++i) {
            int p = sph + 2 * i;
            int c = c0 + 2 * p;
            float wa = g[c]     * hidw[(size_t)c * HH + sj];
            float wb = g[c + 1] * hidw[(size_t)(c + 1) * HH + sj];
            uint2 hl = split_pack(wa, wb);
            sB[sj * 20 + p]        = hl.x;
            sB[2560 + sj * 20 + p] = hl.y;
        }
        __syncthreads();

        bf16x8 Ahi = *(const bf16x8*)&sA[arow * 20 + koff * 4];
        bf16x8 Alo = *(const bf16x8*)&sA[1280 + arow * 20 + koff * 4];
        #pragma unroll
        for (int jt = 0; jt < 8; ++jt) {
            const int brow = jt * 16 + (lane & 15);
            bf16x8 Bhi = *(const bf16x8*)&sB[brow * 20 + koff * 4];
            bf16x8 Blo = *(const bf16x8*)&sB[2560 + brow * 20 + koff * 4];
            acc[jt] = __builtin_amdgcn_mfma_f32_16x16x32_bf16(Alo, Bhi, acc[jt], 0, 0, 0);
            acc[jt] = __builtin_amdgcn_mfma_f32_16x16x32_bf16(Ahi, Blo, acc[jt], 0, 0, 0);
            acc[jt] = __builtin_amdgcn_mfma_f32_16x16x32_bf16(Ahi, Bhi, acc[jt], 0, 0, 0);
        }
        __syncthreads();
    }

    // --- epilogue: gelu, attn logit (reduce over j), sigmoid
    float pl[4] = {0.f, 0.f, 0.f, 0.f};
    #pragma unroll
    for (int jt = 0; jt < 8; ++jt) {
        float fw = finw[jt * 16 + (lane & 15)];
        #pragma unroll
        for (int r = 0; r < 4; ++r)
            pl[r] = fmaf(gelu_exact(acc[jt][r]), fw, pl[r]);
    }
    #pragma unroll
    for (int r = 0; r < 4; ++r) {
        pl[r] += __shfl_xor(pl[r], 1);
        pl[r] += __shfl_xor(pl[r], 2);
        pl[r] += __shfl_xor(pl[r], 4);
        pl[r] += __shfl_xor(pl[r], 8);
    }
    const float fb0 = finb[0];
    if ((lane & 15) == 0) {
        #pragma unroll
        for (int r = 0; r < 4; ++r) {
            int lpx = w * 16 + (lane >> 4) * 4 + r;
            int px  = px0 + lpx;
            float a = (px < HW) ? 1.0f / (1.0f + expf(-(pl[r] + fb0))) : 0.0f;
            sAttn[lpx] = a;
            if (WRITE_ATTN && px < HW) attn_out[bq * HW + px] = a;
        }
    }
    __syncthreads();

    // --- S_a
    if (tid < 64) {
        float sa = sAttn[tid];
        #pragma unroll
        for (int d = 1; d < 64; d <<= 1) sa += __shfl_xor(sa, d);
        if (tid == 0) atomicAdd(&Sout[bq * (C + 1) + C], sa);
    }

    // --- S_fc[c]: coalesced column loads, wave shfl-reduce per channel
    const int pxc = min(px0 + lane, HW - 1);
    constexpr int CPW = C / 4;
    #pragma unroll 1
    for (int ci = 0; ci < CPW; ++ci) {
        const int c2 = w * CPW + ci;
        float s = fbase[(size_t)c2 * HW + pxc] * sAttn[lane];  // sAttn==0 masks pad
        #pragma unroll
        for (int d = 1; d < 64; d <<= 1) s += __shfl_xor(s, d);
        if (lane == 0) atomicAdd(&Sout[bq * (C + 1) + c2], s);
    }
}

__global__ __launch_bounds__(256)
void pool_fused(const float* __restrict__ feat0, const float* __restrict__ feat1,
                const float* __restrict__ feat2,
                const float* __restrict__ gb0, const float* __restrict__ gb1,
                const float* __restrict__ gb2,
                const float* __restrict__ b20, const float* __restrict__ b21,
                const float* __restrict__ b22,
                const float* __restrict__ hw0_, const float* __restrict__ hw1_,
                const float* __restrict__ hw2_,
                const float* __restrict__ finw0, const float* __restrict__ finb0,
                const float* __restrict__ finw1, const float* __restrict__ finb1,
                const float* __restrict__ finw2, const float* __restrict__ finb2,
                float* __restrict__ S0, float* __restrict__ S1, float* __restrict__ S2,
                float* __restrict__ attn2)
{
    __shared__ __align__(16) unsigned sA[2560];   // [hi|lo][64px][20 u32]
    __shared__ __align__(16) unsigned sB[5120];   // [hi|lo][128j][20 u32]
    __shared__ float sAttn[64];
    const int blk = blockIdx.x;
    if (blk < 448) {                                // scale 2 first (most K-steps)
        int bq = blk / 7, t = blk % 7;              // 7 tiles of 64 px (400 -> pad)
        pool_body<256, true>(feat2, 400, gb2, b22, hw2_, finw2, finb2,
                             S2, attn2, bq, t, sA, sB, sAttn);
    } else if (blk < 2048) {
        int bb = blk - 448; int bq = bb / 25, t = bb % 25;    // 25 tiles (1600)
        pool_body<128, false>(feat1, 1600, gb1, b21, hw1_, finw1, finb1,
                              S1, nullptr, bq, t, sA, sB, sAttn);
    } else {
        int bb = blk - 2048; int bq = bb / 100, t = bb % 100; // 100 tiles (6400)
        pool_body<64, false>(feat0, 6400, gb0, b20, hw0_, finw0, finb0,
                             S0, nullptr, bq, t, sA, sB, sAttn);
    }
}

// ---------------------------------------------------------------------------
// MLP layer 1 (unchanged)
// ---------------------------------------------------------------------------
__global__ __launch_bounds__(256)
void mlp1_kernel(const float* __restrict__ S0, const float* __restrict__ S1,
                 const float* __restrict__ S2,
                 const float* __restrict__ gb0, const float* __restrict__ gb1,
                 const float* __restrict__ gb2,
                 const float* __restrict__ attn2,
                 const float* __restrict__ w1, const float* __restrict__ b1,
                 float* __restrict__ X1)
{
    __shared__ float sCat[848];
    __shared__ float sP[256];
    const int tid = threadIdx.x, bq = blockIdx.x;

    for (int i = tid; i < 448; i += 256) {
        int sc, c;
        if (i < 64)       { sc = 0; c = i; }
        else if (i < 192) { sc = 1; c = i - 64; }
        else              { sc = 2; c = i - 192; }
        const int C = 64 << sc;
        const float* So = (sc == 0) ? S0 : (sc == 1) ? S1 : S2;
        const float* g  = (sc == 0) ? gb0 : (sc == 1) ? gb1 : gb2;
        float Sa = So[bq * (C + 1) + C];
        float Sf = So[bq * (C + 1) + c];
        float gamma = g[bq * 2 * C + c];
        float beta  = g[bq * 2 * C + C + c];
        sCat[i] = (gamma * Sf + beta * Sa) / (Sa + EPS);
    }
    for (int i = tid; i < 400; i += 256) sCat[448 + i] = attn2[bq * 400 + i];
    __syncthreads();

    const int o = blockIdx.y * 128 + (tid & 127), half = tid >> 7;
    const int k0 = half * 424;
    float a0 = 0.f, a1 = 0.f;
    #pragma unroll 2
    for (int k = 0; k < 424; k += 2) {
        a0 = fmaf(sCat[k0 + k],     w1[(k0 + k) * 512 + o],     a0);
        a1 = fmaf(sCat[k0 + k + 1], w1[(k0 + k + 1) * 512 + o], a1);
    }
    sP[tid] = a0 + a1;
    __syncthreads();
    if (tid < 128) {
        int oo = blockIdx.y * 128 + tid;
        X1[bq * 512 + oo] = sP[tid] + sP[tid + 128] + b1[oo];
    }
}

// ---------------------------------------------------------------------------
// MLP layers 2+3 (unchanged)
// ---------------------------------------------------------------------------
__global__ __launch_bounds__(256)
void mlp23_kernel(const float* __restrict__ X1,
                  const float* __restrict__ w2, const float* __restrict__ b2,
                  const float* __restrict__ w3, const float* __restrict__ b3,
                  float* __restrict__ out)
{
    __shared__ float sX1[512];
    __shared__ float sX2[256];
    __shared__ float sR[4];
    const int tid = threadIdx.x, bq = blockIdx.x;
    for (int i = tid; i < 512; i += 256) sX1[i] = gelu_exact(X1[bq * 512 + i]);
    __syncthreads();
    float a0 = b2[tid], a1 = 0.f, a2 = 0.f, a3 = 0.f;
    #pragma unroll 4
    for (int k = 0; k < 512; k += 4) {
        a0 = fmaf(sX1[k],     w2[(k)     * 256 + tid], a0);
        a1 = fmaf(sX1[k + 1], w2[(k + 1) * 256 + tid], a1);
        a2 = fmaf(sX1[k + 2], w2[(k + 2) * 256 + tid], a2);
        a3 = fmaf(sX1[k + 3], w2[(k + 3) * 256 + tid], a3);
    }
    sX2[tid] = gelu_exact((a0 + a1) + (a2 + a3));
    __syncthreads();
    float p = sX2[tid] * w3[tid];
    #pragma unroll
    for (int d = 1; d < 64; d <<= 1) p += __shfl_xor(p, d);
    if ((tid & 63) == 0) sR[tid >> 6] = p;
    __syncthreads();
    if (tid == 0) out[bq] = sR[0] + sR[1] + sR[2] + sR[3] + b3[0];
}

// ---------------------------------------------------------------------------
extern "C" void kernel_launch(void* const* d_in, const int* in_sizes, int n_in,
                              void* d_out, int out_size, void* d_ws, size_t ws_size,
                              hipStream_t stream)
{
    const float* feat0 = (const float*)d_in[0];
    const float* feat1 = (const float*)d_in[1];
    const float* feat2 = (const float*)d_in[2];
    const float* qe    = (const float*)d_in[3];
    const float* film_w0 = (const float*)d_in[4];
    const float* film_b0 = (const float*)d_in[5];
    const float* hid_w0  = (const float*)d_in[6];
    const float* hid_b0  = (const float*)d_in[7];
    const float* fin_w0  = (const float*)d_in[8];
    const float* fin_b0  = (const float*)d_in[9];
    const float* film_w1 = (const float*)d_in[10];
    const float* film_b1 = (const float*)d_in[11];
    const float* hid_w1  = (const float*)d_in[12];
    const float* hid_b1  = (const float*)d_in[13];
    const float* fin_w1  = (const float*)d_in[14];
    const float* fin_b1  = (const float*)d_in[15];
    const float* film_w2 = (const float*)d_in[16];
    const float* film_b2 = (const float*)d_in[17];
    const float* hid_w2  = (const float*)d_in[18];
    const float* hid_b2  = (const float*)d_in[19];
    const float* fin_w2  = (const float*)d_in[20];
    const float* fin_b2  = (const float*)d_in[21];
    const float* mlp_w1  = (const float*)d_in[22];
    const float* mlp_b1  = (const float*)d_in[23];
    const float* mlp_w2  = (const float*)d_in[24];
    const float* mlp_b2  = (const float*)d_in[25];
    const float* mlp_w3  = (const float*)d_in[26];
    const float* mlp_b3  = (const float*)d_in[27];

    float* ws = (float*)d_ws;
    float* S0    = ws;              // [64][65]
    float* S1    = ws + 4160;       // [64][129]
    float* S2    = ws + 12416;      // [64][257]   (Sout end 28864)
    float* gb0   = ws + 28864;      // [64][128]
    float* gb1   = ws + 37056;      // [64][256]
    float* gb2   = ws + 53440;      // [64][512]
    float* b20   = ws + 86208;      // [64][128]
    float* b21   = ws + 94400;
    float* b22   = ws + 102592;
    float* attn2 = ws + 110784;     // [64][400]
    float* X1    = ws + 136384;     // [64][512]

    hipMemsetAsync(d_ws, 0, 28864 * sizeof(float), stream);

    film2_kernel<<<dim3(BQ, 7), 256, 0, stream>>>(
        qe, film_w0, film_b0, film_w1, film_b1, film_w2, film_b2,
        gb0, gb1, gb2);

    b2_kernel<<<dim3(BQ, 3), 256, 0, stream>>>(
        gb0, gb1, gb2,
        hid_w0, hid_b0, hid_w1, hid_b1, hid_w2, hid_b2,
        b20, b21, b22);

    pool_fused<<<8448, 256, 0, stream>>>(
        feat0, feat1, feat2,
        gb0, gb1, gb2, b20, b21, b22,
        hid_w0, hid_w1, hid_w2,
        fin_w0, fin_b0, fin_w1, fin_b1, fin_w2, fin_b2,
        S0, S1, S2, attn2);

    mlp1_kernel<<<dim3(BQ, 4), 256, 0, stream>>>(
        S0, S1, S2, gb0, gb1, gb2, attn2, mlp_w1, mlp_b1, X1);

    mlp23_kernel<<<BQ, 256, 0, stream>>>(
        X1, mlp_w2, mlp_b2, mlp_w3, mlp_b3, (float*)d_out);
}

// Round 10
// 427.715 us; speedup vs baseline: 1.0518x; 1.0518x over previous
//
#include <hip/hip_runtime.h>
#include <math.h>

#define BQ 64
#define HH 128
#define EPS 1e-8f

typedef short bf16x8 __attribute__((ext_vector_type(8)));
typedef float f32x4  __attribute__((ext_vector_type(4)));

__device__ __forceinline__ float gelu_exact(float x) {
    return 0.5f * x * (1.0f + erff(x * 0.70710678118654752440f));
}

// round-to-nearest-even fp32 -> bf16 (low 16 bits)
__device__ __forceinline__ unsigned bf16_rne(float x) {
    unsigned u = __float_as_uint(x);
    return (u + 0x7FFFu + ((u >> 16) & 1u)) >> 16;
}
// split two floats into packed bf16 hi-plane / lo-plane words
__device__ __forceinline__ uint2 split_pack(float a, float b) {
    unsigned ha = bf16_rne(a);
    float fa = __uint_as_float(ha << 16);
    unsigned la = bf16_rne(a - fa);
    unsigned hb = bf16_rne(b);
    float fb = __uint_as_float(hb << 16);
    unsigned lb = bf16_rne(b - fb);
    uint2 r; r.x = ha | (hb << 16); r.y = la | (lb << 16);
    return r;
}

// ---------------------------------------------------------------------------
// FiLM projection (unchanged)
// ---------------------------------------------------------------------------
__global__ __launch_bounds__(256)
void film2_kernel(const float* __restrict__ qe,
                  const float* __restrict__ fw0, const float* __restrict__ fb0,
                  const float* __restrict__ fw1, const float* __restrict__ fb1,
                  const float* __restrict__ fw2, const float* __restrict__ fb2,
                  float* __restrict__ gb0, float* __restrict__ gb1, float* __restrict__ gb2)
{
    __shared__ float sq[768];
    __shared__ float sP[256];
    const int tid = threadIdx.x, bq = blockIdx.x, chunk = blockIdx.y;
    int s, o0;
    if (chunk == 0)      { s = 0; o0 = 0; }
    else if (chunk <= 2) { s = 1; o0 = (chunk - 1) * 128; }
    else                 { s = 2; o0 = (chunk - 3) * 128; }
    const float* fw  = s == 0 ? fw0 : s == 1 ? fw1 : fw2;
    const float* fbv = s == 0 ? fb0 : s == 1 ? fb1 : fb2;
    float* gb        = s == 0 ? gb0 : s == 1 ? gb1 : gb2;
    const int twoC = 128 << s;

    for (int i = tid; i < 768; i += 256) sq[i] = qe[bq * 768 + i];
    __syncthreads();

    const int o = o0 + (tid & 127), half = tid >> 7;
    const int e0 = half * 384;
    float a0 = 0.f, a1 = 0.f;
    #pragma unroll 2
    for (int e = 0; e < 384; e += 2) {
        a0 = fmaf(sq[e0 + e],     fw[(e0 + e) * twoC + o],     a0);
        a1 = fmaf(sq[e0 + e + 1], fw[(e0 + e + 1) * twoC + o], a1);
    }
    sP[tid] = a0 + a1;
    __syncthreads();
    if (tid < 128) {
        int oo = o0 + tid;
        gb[bq * twoC + oo] = sP[tid] + sP[tid + 128] + fbv[oo];
    }
}

// ---------------------------------------------------------------------------
// b2[bq, j] = hid_b[j] + sum_c beta[c] * hid_w[c, j]  (unchanged)
// ---------------------------------------------------------------------------
__global__ __launch_bounds__(256)
void b2_kernel(const float* __restrict__ gb0, const float* __restrict__ gb1,
               const float* __restrict__ gb2,
               const float* __restrict__ hw0_, const float* __restrict__ hb0,
               const float* __restrict__ hw1_, const float* __restrict__ hb1,
               const float* __restrict__ hw2_, const float* __restrict__ hb2,
               float* __restrict__ b20, float* __restrict__ b21, float* __restrict__ b22)
{
    __shared__ float sBeta[256];
    __shared__ float sP[256];
    const int tid = threadIdx.x, bq = blockIdx.x, s = blockIdx.y;
    const float* gb = s == 0 ? gb0 : s == 1 ? gb1 : gb2;
    const float* hw = s == 0 ? hw0_ : s == 1 ? hw1_ : hw2_;
    const float* hb = s == 0 ? hb0 : s == 1 ? hb1 : hb2;
    float* b2       = s == 0 ? b20 : s == 1 ? b21 : b22;
    const int C = 64 << s;

    for (int i = tid; i < C; i += 256) sBeta[i] = gb[bq * 2 * C + C + i];
    __syncthreads();
    const int j = tid & 127, half = tid >> 7;
    const int c0 = half * (C / 2);
    float acc = 0.f;
    for (int c = 0; c < C / 2; ++c)
        acc = fmaf(sBeta[c0 + c], hw[(c0 + c) * HH + j], acc);
    sP[tid] = acc;
    __syncthreads();
    if (tid < 128) b2[bq * HH + tid] = hb[tid] + sP[tid] + sP[tid + 128];
}

// ---------------------------------------------------------------------------
// pack_feat: feat fp32 [b][c][px] -> hi/lo bf16 planes [b][c/8][px][8]
// one thread per (b,cg,px); reads coalesced along px, writes 16B contiguous.
// ---------------------------------------------------------------------------
__global__ __launch_bounds__(256)
void pack_feat_kernel(const float* __restrict__ f0, const float* __restrict__ f1,
                      const float* __restrict__ f2,
                      unsigned short* __restrict__ p0h, unsigned short* __restrict__ p0l,
                      unsigned short* __restrict__ p1h, unsigned short* __restrict__ p1l,
                      unsigned short* __restrict__ p2h, unsigned short* __restrict__ p2l)
{
    int i = blockIdx.x * 256 + threadIdx.x;
    const float* f; unsigned short *oh, *ol; int HW; int idx;
    if (i < 102400)      { f = f0; oh = p0h; ol = p0l; HW = 6400; idx = i; }          // 2*8*6400
    else if (i < 153600) { f = f1; oh = p1h; ol = p1l; HW = 1600; idx = i - 102400; } // 2*16*1600
    else if (i < 179200) { f = f2; oh = p2h; ol = p2l; HW = 400;  idx = i - 153600; } // 2*32*400
    else return;
    const int px = idx % HW;
    const int cgb = idx / HW;                 // b*CG + cg  (linear)
    const float* src = f + ((size_t)cgb * 8) * HW + px;
    float a[8];
    #pragma unroll
    for (int k = 0; k < 8; ++k) a[k] = src[(size_t)k * HW];
    unsigned hwd[4], lwd[4];
    #pragma unroll
    for (int k = 0; k < 4; ++k) {
        uint2 p = split_pack(a[2 * k], a[2 * k + 1]);
        hwd[k] = p.x; lwd[k] = p.y;
    }
    *(uint4*)&oh[(size_t)idx * 8] = make_uint4(hwd[0], hwd[1], hwd[2], hwd[3]);
    *(uint4*)&ol[(size_t)idx * 8] = make_uint4(lwd[0], lwd[1], lwd[2], lwd[3]);
}

// ---------------------------------------------------------------------------
// pack_gw: gammaW hi/lo bf16 planes [bq][c/8][j][8]
// one thread per (bq,cg,j).
// ---------------------------------------------------------------------------
__global__ __launch_bounds__(256)
void pack_gw_kernel(const float* __restrict__ gb0, const float* __restrict__ gb1,
                    const float* __restrict__ gb2,
                    const float* __restrict__ hw0_, const float* __restrict__ hw1_,
                    const float* __restrict__ hw2_,
                    unsigned short* __restrict__ g0h, unsigned short* __restrict__ g0l,
                    unsigned short* __restrict__ g1h, unsigned short* __restrict__ g1l,
                    unsigned short* __restrict__ g2h, unsigned short* __restrict__ g2l)
{
    int i = blockIdx.x * 256 + threadIdx.x;
    const float *gb, *hw; unsigned short *oh, *ol; int C, idx;
    if (i < 65536)       { gb = gb0; hw = hw0_; oh = g0h; ol = g0l; C = 64;  idx = i; }          // 64*8*128
    else if (i < 196608) { gb = gb1; hw = hw1_; oh = g1h; ol = g1l; C = 128; idx = i - 65536; }  // 64*16*128
    else if (i < 458752) { gb = gb2; hw = hw2_; oh = g2h; ol = g2l; C = 256; idx = i - 196608; } // 64*32*128
    else return;
    const int j  = idx & 127;
    const int cg = (idx >> 7) % (C / 8);
    const int bq = idx / (128 * (C / 8));
    const int c0 = cg * 8;
    const float* g = gb + bq * 2 * C;          // gamma at [0,C)
    float a[8];
    #pragma unroll
    for (int k = 0; k < 8; ++k) a[k] = g[c0 + k] * hw[(size_t)(c0 + k) * HH + j];
    unsigned hwd[4], lwd[4];
    #pragma unroll
    for (int k = 0; k < 4; ++k) {
        uint2 p = split_pack(a[2 * k], a[2 * k + 1]);
        hwd[k] = p.x; lwd[k] = p.y;
    }
    *(uint4*)&oh[(size_t)idx * 8] = make_uint4(hwd[0], hwd[1], hwd[2], hwd[3]);
    *(uint4*)&ol[(size_t)idx * 8] = make_uint4(lwd[0], lwd[1], lwd[2], lwd[3]);
}

// ---------------------------------------------------------------------------
// MFMA FiLM pool, zero-LDS main loop. Block = 4 waves, 64-px tile.
// A fragments from fpack [b][cg][px][8]; B fragments from gwpack [bq][cg][j][8]
// (both already in fragment order: row = lane&15, k-slot = lane>>4, 8 contig).
// 3-term bf16 hi/lo split per r9 (verified absmax 0.0).
// ---------------------------------------------------------------------------
template<int C, bool WRITE_ATTN>
__device__ __forceinline__
void pool_body(const float* __restrict__ feat, int HW,
               const unsigned short* __restrict__ fh, const unsigned short* __restrict__ fl,
               const unsigned short* __restrict__ gwh, const unsigned short* __restrict__ gwl,
               const float* __restrict__ b2, const float* __restrict__ finw,
               const float* __restrict__ finb,
               float* __restrict__ Sout, float* __restrict__ attn_out,
               int bq, int tile, float* sAttn)
{
    const int tid  = threadIdx.x;
    const int w    = tid >> 6;
    const int lane = tid & 63;
    const int l15  = lane & 15, l4 = lane >> 4;
    const int b    = bq >> 5;
    const int px0  = tile * 64;
    constexpr int CG = C / 8;
    const float* fbase = feat + (size_t)b * C * HW;

    f32x4 acc[8];
    #pragma unroll
    for (int jt = 0; jt < 8; ++jt) {
        float bv = b2[bq * HH + jt * 16 + l15];
        acc[jt] = (f32x4){bv, bv, bv, bv};
    }

    const int apx = min(px0 + w * 16 + l15, HW - 1);
    const unsigned short* fhp = fh + (size_t)b * CG * HW * 8;
    const unsigned short* flp = fl + (size_t)b * CG * HW * 8;
    const unsigned short* gbh = gwh + (size_t)bq * CG * 128 * 8;
    const unsigned short* gbl = gwl + (size_t)bq * CG * 128 * 8;

    for (int ks = 0; ks < CG / 4; ++ks) {
        const size_t aoff = (((size_t)(ks * 4 + l4)) * HW + apx) * 8;
        const bf16x8 Ahi = *(const bf16x8*)(fhp + aoff);
        const bf16x8 Alo = *(const bf16x8*)(flp + aoff);
        const size_t bbase = (((size_t)(ks * 4 + l4)) * 128 + l15) * 8;
        #pragma unroll
        for (int jt = 0; jt < 8; ++jt) {
            const size_t boff = bbase + (size_t)jt * 16 * 8;
            const bf16x8 Bhi = *(const bf16x8*)(gbh + boff);
            const bf16x8 Blo = *(const bf16x8*)(gbl + boff);
            acc[jt] = __builtin_amdgcn_mfma_f32_16x16x32_bf16(Alo, Bhi, acc[jt], 0, 0, 0);
            acc[jt] = __builtin_amdgcn_mfma_f32_16x16x32_bf16(Ahi, Blo, acc[jt], 0, 0, 0);
            acc[jt] = __builtin_amdgcn_mfma_f32_16x16x32_bf16(Ahi, Bhi, acc[jt], 0, 0, 0);
        }
    }

    // epilogue: gelu, attn logit (reduce over j within 16-lane groups), sigmoid
    float pl[4] = {0.f, 0.f, 0.f, 0.f};
    #pragma unroll
    for (int jt = 0; jt < 8; ++jt) {
        float fw = finw[jt * 16 + l15];
        #pragma unroll
        for (int r = 0; r < 4; ++r)
            pl[r] = fmaf(gelu_exact(acc[jt][r]), fw, pl[r]);
    }
    #pragma unroll
    for (int r = 0; r < 4; ++r) {
        pl[r] += __shfl_xor(pl[r], 1);
        pl[r] += __shfl_xor(pl[r], 2);
        pl[r] += __shfl_xor(pl[r], 4);
        pl[r] += __shfl_xor(pl[r], 8);
    }
    const float fb0 = finb[0];
    if (l15 == 0) {
        #pragma unroll
        for (int r = 0; r < 4; ++r) {
            int lpx = w * 16 + l4 * 4 + r;
            int px  = px0 + lpx;
            float a = (px < HW) ? 1.0f / (1.0f + expf(-(pl[r] + fb0))) : 0.0f;
            sAttn[lpx] = a;
            if (WRITE_ATTN && px < HW) attn_out[bq * HW + px] = a;
        }
    }
    __syncthreads();

    // S_a
    if (tid < 64) {
        float sa = sAttn[tid];
        #pragma unroll
        for (int d = 1; d < 64; d <<= 1) sa += __shfl_xor(sa, d);
        if (tid == 0) atomicAdd(&Sout[bq * (C + 1) + C], sa);
    }

    // S_fc[c]: coalesced column loads, wave shfl-reduce per channel
    const int pxc = min(px0 + lane, HW - 1);
    constexpr int CPW = C / 4;
    #pragma unroll 1
    for (int ci = 0; ci < CPW; ++ci) {
        const int c2 = w * CPW + ci;
        float s = fbase[(size_t)c2 * HW + pxc] * sAttn[lane];
        #pragma unroll
        for (int d = 1; d < 64; d <<= 1) s += __shfl_xor(s, d);
        if (lane == 0) atomicAdd(&Sout[bq * (C + 1) + c2], s);
    }
}

__global__ __launch_bounds__(256)
void pool_fused(const float* __restrict__ feat0, const float* __restrict__ feat1,
                const float* __restrict__ feat2,
                const unsigned short* __restrict__ f0h, const unsigned short* __restrict__ f0l,
                const unsigned short* __restrict__ f1h, const unsigned short* __restrict__ f1l,
                const unsigned short* __restrict__ f2h, const unsigned short* __restrict__ f2l,
                const unsigned short* __restrict__ g0h, const unsigned short* __restrict__ g0l,
                const unsigned short* __restrict__ g1h, const unsigned short* __restrict__ g1l,
                const unsigned short* __restrict__ g2h, const unsigned short* __restrict__ g2l,
                const float* __restrict__ b20, const float* __restrict__ b21,
                const float* __restrict__ b22,
                const float* __restrict__ finw0, const float* __restrict__ finb0,
                const float* __restrict__ finw1, const float* __restrict__ finb1,
                const float* __restrict__ finw2, const float* __restrict__ finb2,
                float* __restrict__ S0, float* __restrict__ S1, float* __restrict__ S2,
                float* __restrict__ attn2)
{
    __shared__ float sAttn[64];
    const int blk = blockIdx.x;
    if (blk < 448) {                                 // scale 2 first (most K-steps)
        int bq = blk / 7, t = blk % 7;
        pool_body<256, true>(feat2, 400, f2h, f2l, g2h, g2l, b22, finw2, finb2,
                             S2, attn2, bq, t, sAttn);
    } else if (blk < 2048) {
        int bb = blk - 448; int bq = bb / 25, t = bb % 25;
        pool_body<128, false>(feat1, 1600, f1h, f1l, g1h, g1l, b21, finw1, finb1,
                              S1, nullptr, bq, t, sAttn);
    } else {
        int bb = blk - 2048; int bq = bb / 100, t = bb % 100;
        pool_body<64, false>(feat0, 6400, f0h, f0l, g0h, g0l, b20, finw0, finb0,
                             S0, nullptr, bq, t, sAttn);
    }
}

// ---------------------------------------------------------------------------
// MLP layer 1 (unchanged)
// ---------------------------------------------------------------------------
__global__ __launch_bounds__(256)
void mlp1_kernel(const float* __restrict__ S0, const float* __restrict__ S1,
                 const float* __restrict__ S2,
                 const float* __restrict__ gb0, const float* __restrict__ gb1,
                 const float* __restrict__ gb2,
                 const float* __restrict__ attn2,
                 const float* __restrict__ w1, const float* __restrict__ b1,
                 float* __restrict__ X1)
{
    __shared__ float sCat[848];
    __shared__ float sP[256];
    const int tid = threadIdx.x, bq = blockIdx.x;

    for (int i = tid; i < 448; i += 256) {
        int sc, c;
        if (i < 64)       { sc = 0; c = i; }
        else if (i < 192) { sc = 1; c = i - 64; }
        else              { sc = 2; c = i - 192; }
        const int C = 64 << sc;
        const float* So = (sc == 0) ? S0 : (sc == 1) ? S1 : S2;
        const float* g  = (sc == 0) ? gb0 : (sc == 1) ? gb1 : gb2;
        float Sa = So[bq * (C + 1) + C];
        float Sf = So[bq * (C + 1) + c];
        float gamma = g[bq * 2 * C + c];
        float beta  = g[bq * 2 * C + C + c];
        sCat[i] = (gamma * Sf + beta * Sa) / (Sa + EPS);
    }
    for (int i = tid; i < 400; i += 256) sCat[448 + i] = attn2[bq * 400 + i];
    __syncthreads();

    const int o = blockIdx.y * 128 + (tid & 127), half = tid >> 7;
    const int k0 = half * 424;
    float a0 = 0.f, a1 = 0.f;
    #pragma unroll 2
    for (int k = 0; k < 424; k += 2) {
        a0 = fmaf(sCat[k0 + k],     w1[(k0 + k) * 512 + o],     a0);
        a1 = fmaf(sCat[k0 + k + 1], w1[(k0 + k + 1) * 512 + o], a1);
    }
    sP[tid] = a0 + a1;
    __syncthreads();
    if (tid < 128) {
        int oo = blockIdx.y * 128 + tid;
        X1[bq * 512 + oo] = sP[tid] + sP[tid + 128] + b1[oo];
    }
}

// ---------------------------------------------------------------------------
// MLP layers 2+3 (unchanged)
// ---------------------------------------------------------------------------
__global__ __launch_bounds__(256)
void mlp23_kernel(const float* __restrict__ X1,
                  const float* __restrict__ w2, const float* __restrict__ b2,
                  const float* __restrict__ w3, const float* __restrict__ b3,
                  float* __restrict__ out)
{
    __shared__ float sX1[512];
    __shared__ float sX2[256];
    __shared__ float sR[4];
    const int tid = threadIdx.x, bq = blockIdx.x;
    for (int i = tid; i < 512; i += 256) sX1[i] = gelu_exact(X1[bq * 512 + i]);
    __syncthreads();
    float a0 = b2[tid], a1 = 0.f, a2 = 0.f, a3 = 0.f;
    #pragma unroll 4
    for (int k = 0; k < 512; k += 4) {
        a0 = fmaf(sX1[k],     w2[(k)     * 256 + tid], a0);
        a1 = fmaf(sX1[k + 1], w2[(k + 1) * 256 + tid], a1);
        a2 = fmaf(sX1[k + 2], w2[(k + 2) * 256 + tid], a2);
        a3 = fmaf(sX1[k + 3], w2[(k + 3) * 256 + tid], a3);
    }
    sX2[tid] = gelu_exact((a0 + a1) + (a2 + a3));
    __syncthreads();
    float p = sX2[tid] * w3[tid];
    #pragma unroll
    for (int d = 1; d < 64; d <<= 1) p += __shfl_xor(p, d);
    if ((tid & 63) == 0) sR[tid >> 6] = p;
    __syncthreads();
    if (tid == 0) out[bq] = sR[0] + sR[1] + sR[2] + sR[3] + b3[0];
}

// ---------------------------------------------------------------------------
extern "C" void kernel_launch(void* const* d_in, const int* in_sizes, int n_in,
                              void* d_out, int out_size, void* d_ws, size_t ws_size,
                              hipStream_t stream)
{
    const float* feat0 = (const float*)d_in[0];
    const float* feat1 = (const float*)d_in[1];
    const float* feat2 = (const float*)d_in[2];
    const float* qe    = (const float*)d_in[3];
    const float* film_w0 = (const float*)d_in[4];
    const float* film_b0 = (const float*)d_in[5];
    const float* hid_w0  = (const float*)d_in[6];
    const float* hid_b0  = (const float*)d_in[7];
    const float* fin_w0  = (const float*)d_in[8];
    const float* fin_b0  = (const float*)d_in[9];
    const float* film_w1 = (const float*)d_in[10];
    const float* film_b1 = (const float*)d_in[11];
    const float* hid_w1  = (const float*)d_in[12];
    const float* hid_b1  = (const float*)d_in[13];
    const float* fin_w1  = (const float*)d_in[14];
    const float* fin_b1  = (const float*)d_in[15];
    const float* film_w2 = (const float*)d_in[16];
    const float* film_b2 = (const float*)d_in[17];
    const float* hid_w2  = (const float*)d_in[18];
    const float* hid_b2  = (const float*)d_in[19];
    const float* fin_w2  = (const float*)d_in[20];
    const float* fin_b2  = (const float*)d_in[21];
    const float* mlp_w1  = (const float*)d_in[22];
    const float* mlp_b1  = (const float*)d_in[23];
    const float* mlp_w2  = (const float*)d_in[24];
    const float* mlp_b2  = (const float*)d_in[25];
    const float* mlp_w3  = (const float*)d_in[26];
    const float* mlp_b3  = (const float*)d_in[27];

    float* ws = (float*)d_ws;
    float* S0    = ws;              // [64][65]
    float* S1    = ws + 4160;       // [64][129]
    float* S2    = ws + 12416;      // [64][257]   (Sout end 28864)
    float* gb0   = ws + 28864;      // [64][128]
    float* gb1   = ws + 37056;      // [64][256]
    float* gb2   = ws + 53440;      // [64][512]
    float* b20   = ws + 86208;      // [64][128]
    float* b21   = ws + 94400;
    float* b22   = ws + 102592;
    float* attn2 = ws + 110784;     // [64][400]
    float* X1    = ws + 136384;     // [64][512]   (end 169152 floats)

    // packed bf16 planes (ushort units) after the float region
    unsigned short* us = (unsigned short*)(ws + 169216);  // 16B-aligned
    unsigned short* f0h = us;                   // 2*64*6400   = 819200
    unsigned short* f0l = f0h + 819200;
    unsigned short* f1h = f0l + 819200;         // 2*128*1600  = 409600
    unsigned short* f1l = f1h + 409600;
    unsigned short* f2h = f1l + 409600;         // 2*256*400   = 204800
    unsigned short* f2l = f2h + 204800;
    unsigned short* g0h = f2l + 204800;         // 64*64*128   = 524288
    unsigned short* g0l = g0h + 524288;
    unsigned short* g1h = g0l + 524288;         // 64*128*128  = 1048576
    unsigned short* g1l = g1h + 1048576;
    unsigned short* g2h = g1l + 1048576;        // 64*256*128  = 2097152
    unsigned short* g2l = g2h + 2097152;        // end ≈ 21.5 MB

    hipMemsetAsync(d_ws, 0, 28864 * sizeof(float), stream);

    pack_feat_kernel<<<700, 256, 0, stream>>>(
        feat0, feat1, feat2, f0h, f0l, f1h, f1l, f2h, f2l);

    film2_kernel<<<dim3(BQ, 7), 256, 0, stream>>>(
        qe, film_w0, film_b0, film_w1, film_b1, film_w2, film_b2,
        gb0, gb1, gb2);

    pack_gw_kernel<<<1792, 256, 0, stream>>>(
        gb0, gb1, gb2, hid_w0, hid_w1, hid_w2,
        g0h, g0l, g1h, g1l, g2h, g2l);

    b2_kernel<<<dim3(BQ, 3), 256, 0, stream>>>(
        gb0, gb1, gb2,
        hid_w0, hid_b0, hid_w1, hid_b1, hid_w2, hid_b2,
        b20, b21, b22);

    pool_fused<<<8448, 256, 0, stream>>>(
        feat0, feat1, feat2,
        f0h, f0l, f1h, f1l, f2h, f2l,
        g0h, g0l, g1h, g1l, g2h, g2l,
        b20, b21, b22,
        fin_w0, fin_b0, fin_w1, fin_b1, fin_w2, fin_b2,
        S0, S1, S2, attn2);

    mlp1_kernel<<<dim3(BQ, 4), 256, 0, stream>>>(
        S0, S1, S2, gb0, gb1, gb2, attn2, mlp_w1, mlp_b1, X1);

    mlp23_kernel<<<BQ, 256, 0, stream>>>(
        X1, mlp_w2, mlp_b2, mlp_w3, mlp_b3, (float*)d_out);
}

// Round 11
// 258.038 us; speedup vs baseline: 1.7435x; 1.6576x over previous
//
#include <hip/hip_runtime.h>
#include <math.h>

#define BQ 64
#define HH 128
#define EPS 1e-8f

typedef short bf16x8 __attribute__((ext_vector_type(8)));
typedef float f32x4  __attribute__((ext_vector_type(4)));

__device__ __forceinline__ float gelu_exact(float x) {
    return 0.5f * x * (1.0f + erff(x * 0.70710678118654752440f));
}

// round-to-nearest-even fp32 -> bf16 (low 16 bits)
__device__ __forceinline__ unsigned bf16_rne(float x) {
    unsigned u = __float_as_uint(x);
    return (u + 0x7FFFu + ((u >> 16) & 1u)) >> 16;
}
// split two floats into packed bf16 hi-plane / lo-plane words
__device__ __forceinline__ uint2 split_pack(float a, float b) {
    unsigned ha = bf16_rne(a);
    float fa = __uint_as_float(ha << 16);
    unsigned la = bf16_rne(a - fa);
    unsigned hb = bf16_rne(b);
    float fb = __uint_as_float(hb << 16);
    unsigned lb = bf16_rne(b - fb);
    uint2 r; r.x = ha | (hb << 16); r.y = la | (lb << 16);
    return r;
}

// ---------------------------------------------------------------------------
// FiLM projection (unchanged)
// ---------------------------------------------------------------------------
__global__ __launch_bounds__(256)
void film2_kernel(const float* __restrict__ qe,
                  const float* __restrict__ fw0, const float* __restrict__ fb0,
                  const float* __restrict__ fw1, const float* __restrict__ fb1,
                  const float* __restrict__ fw2, const float* __restrict__ fb2,
                  float* __restrict__ gb0, float* __restrict__ gb1, float* __restrict__ gb2)
{
    __shared__ float sq[768];
    __shared__ float sP[256];
    const int tid = threadIdx.x, bq = blockIdx.x, chunk = blockIdx.y;
    int s, o0;
    if (chunk == 0)      { s = 0; o0 = 0; }
    else if (chunk <= 2) { s = 1; o0 = (chunk - 1) * 128; }
    else                 { s = 2; o0 = (chunk - 3) * 128; }
    const float* fw  = s == 0 ? fw0 : s == 1 ? fw1 : fw2;
    const float* fbv = s == 0 ? fb0 : s == 1 ? fb1 : fb2;
    float* gb        = s == 0 ? gb0 : s == 1 ? gb1 : gb2;
    const int twoC = 128 << s;

    for (int i = tid; i < 768; i += 256) sq[i] = qe[bq * 768 + i];
    __syncthreads();

    const int o = o0 + (tid & 127), half = tid >> 7;
    const int e0 = half * 384;
    float a0 = 0.f, a1 = 0.f;
    #pragma unroll 2
    for (int e = 0; e < 384; e += 2) {
        a0 = fmaf(sq[e0 + e],     fw[(e0 + e) * twoC + o],     a0);
        a1 = fmaf(sq[e0 + e + 1], fw[(e0 + e + 1) * twoC + o], a1);
    }
    sP[tid] = a0 + a1;
    __syncthreads();
    if (tid < 128) {
        int oo = o0 + tid;
        gb[bq * twoC + oo] = sP[tid] + sP[tid + 128] + fbv[oo];
    }
}

// ---------------------------------------------------------------------------
// b2[bq, j] = hid_b[j] + sum_c beta[c] * hid_w[c, j]  (unchanged)
// ---------------------------------------------------------------------------
__global__ __launch_bounds__(256)
void b2_kernel(const float* __restrict__ gb0, const float* __restrict__ gb1,
               const float* __restrict__ gb2,
               const float* __restrict__ hw0_, const float* __restrict__ hb0,
               const float* __restrict__ hw1_, const float* __restrict__ hb1,
               const float* __restrict__ hw2_, const float* __restrict__ hb2,
               float* __restrict__ b20, float* __restrict__ b21, float* __restrict__ b22)
{
    __shared__ float sBeta[256];
    __shared__ float sP[256];
    const int tid = threadIdx.x, bq = blockIdx.x, s = blockIdx.y;
    const float* gb = s == 0 ? gb0 : s == 1 ? gb1 : gb2;
    const float* hw = s == 0 ? hw0_ : s == 1 ? hw1_ : hw2_;
    const float* hb = s == 0 ? hb0 : s == 1 ? hb1 : hb2;
    float* b2       = s == 0 ? b20 : s == 1 ? b21 : b22;
    const int C = 64 << s;

    for (int i = tid; i < C; i += 256) sBeta[i] = gb[bq * 2 * C + C + i];
    __syncthreads();
    const int j = tid & 127, half = tid >> 7;
    const int c0 = half * (C / 2);
    float acc = 0.f;
    for (int c = 0; c < C / 2; ++c)
        acc = fmaf(sBeta[c0 + c], hw[(c0 + c) * HH + j], acc);
    sP[tid] = acc;
    __syncthreads();
    if (tid < 128) b2[bq * HH + tid] = hb[tid] + sP[tid] + sP[tid + 128];
}

// ---------------------------------------------------------------------------
// pack_feat: feat fp32 [b][c][px] -> hi/lo bf16 planes [b][c/8][px][8]
// ---------------------------------------------------------------------------
__global__ __launch_bounds__(256)
void pack_feat_kernel(const float* __restrict__ f0, const float* __restrict__ f1,
                      const float* __restrict__ f2,
                      unsigned short* __restrict__ p0h, unsigned short* __restrict__ p0l,
                      unsigned short* __restrict__ p1h, unsigned short* __restrict__ p1l,
                      unsigned short* __restrict__ p2h, unsigned short* __restrict__ p2l)
{
    int i = blockIdx.x * 256 + threadIdx.x;
    const float* f; unsigned short *oh, *ol; int HW; int idx;
    if (i < 102400)      { f = f0; oh = p0h; ol = p0l; HW = 6400; idx = i; }
    else if (i < 153600) { f = f1; oh = p1h; ol = p1l; HW = 1600; idx = i - 102400; }
    else if (i < 179200) { f = f2; oh = p2h; ol = p2l; HW = 400;  idx = i - 153600; }
    else return;
    const int px = idx % HW;
    const int cgb = idx / HW;
    const float* src = f + ((size_t)cgb * 8) * HW + px;
    float a[8];
    #pragma unroll
    for (int k = 0; k < 8; ++k) a[k] = src[(size_t)k * HW];
    unsigned hwd[4], lwd[4];
    #pragma unroll
    for (int k = 0; k < 4; ++k) {
        uint2 p = split_pack(a[2 * k], a[2 * k + 1]);
        hwd[k] = p.x; lwd[k] = p.y;
    }
    *(uint4*)&oh[(size_t)idx * 8] = make_uint4(hwd[0], hwd[1], hwd[2], hwd[3]);
    *(uint4*)&ol[(size_t)idx * 8] = make_uint4(lwd[0], lwd[1], lwd[2], lwd[3]);
}

// ---------------------------------------------------------------------------
// pack_gw: gammaW hi/lo bf16 planes [bq][c/8][j][8]
// ---------------------------------------------------------------------------
__global__ __launch_bounds__(256)
void pack_gw_kernel(const float* __restrict__ gb0, const float* __restrict__ gb1,
                    const float* __restrict__ gb2,
                    const float* __restrict__ hw0_, const float* __restrict__ hw1_,
                    const float* __restrict__ hw2_,
                    unsigned short* __restrict__ g0h, unsigned short* __restrict__ g0l,
                    unsigned short* __restrict__ g1h, unsigned short* __restrict__ g1l,
                    unsigned short* __restrict__ g2h, unsigned short* __restrict__ g2l)
{
    int i = blockIdx.x * 256 + threadIdx.x;
    const float *gb, *hw; unsigned short *oh, *ol; int C, idx;
    if (i < 65536)       { gb = gb0; hw = hw0_; oh = g0h; ol = g0l; C = 64;  idx = i; }
    else if (i < 196608) { gb = gb1; hw = hw1_; oh = g1h; ol = g1l; C = 128; idx = i - 65536; }
    else if (i < 458752) { gb = gb2; hw = hw2_; oh = g2h; ol = g2l; C = 256; idx = i - 196608; }
    else return;
    const int j  = idx & 127;
    const int cg = (idx >> 7) % (C / 8);
    const int bq = idx / (128 * (C / 8));
    const int c0 = cg * 8;
    const float* g = gb + bq * 2 * C;
    float a[8];
    #pragma unroll
    for (int k = 0; k < 8; ++k) a[k] = g[c0 + k] * hw[(size_t)(c0 + k) * HH + j];
    unsigned hwd[4], lwd[4];
    #pragma unroll
    for (int k = 0; k < 4; ++k) {
        uint2 p = split_pack(a[2 * k], a[2 * k + 1]);
        hwd[k] = p.x; lwd[k] = p.y;
    }
    *(uint4*)&oh[(size_t)idx * 8] = make_uint4(hwd[0], hwd[1], hwd[2], hwd[3]);
    *(uint4*)&ol[(size_t)idx * 8] = make_uint4(lwd[0], lwd[1], lwd[2], lwd[3]);
}

// ---------------------------------------------------------------------------
// MFMA FiLM pool v3. Block = 8 waves (512 thr), 256-px tile.
// Per ks (32 c): block stages the 16 KB B slab (gammaW hi/lo, linear layout)
// into LDS once (coalesced uint4, conflict-free), then each wave computes
// 2 A-row-tiles x 8 j-tiles from LDS fragments. A fragments direct global.
// acc = 2x8 f32x4 = 64 VGPR (no spill), B amortized over 256 px.
// ---------------------------------------------------------------------------
template<int C, bool WRITE_ATTN>
__device__ __forceinline__
void pool_body(const float* __restrict__ feat, int HW,
               const unsigned short* __restrict__ fh, const unsigned short* __restrict__ fl,
               const unsigned short* __restrict__ gwh, const unsigned short* __restrict__ gwl,
               const float* __restrict__ b2, const float* __restrict__ finw,
               const float* __restrict__ finb,
               float* __restrict__ Sout, float* __restrict__ attn_out,
               int bq, int tile,
               unsigned short* sB, float* sAttn)
{
    const int tid  = threadIdx.x;
    const int w    = tid >> 6;                    // wave 0..7
    const int lane = tid & 63;
    const int l15  = lane & 15, l4 = lane >> 4;
    const int b    = bq >> 5;
    const int px0  = tile * 256;
    constexpr int CG = C / 8;
    const float* fbase = feat + (size_t)b * C * HW;

    f32x4 acc[2][8];
    #pragma unroll
    for (int jt = 0; jt < 8; ++jt) {
        float bv = b2[bq * HH + jt * 16 + l15];
        acc[0][jt] = (f32x4){bv, bv, bv, bv};
        acc[1][jt] = (f32x4){bv, bv, bv, bv};
    }

    const int apx0 = min(px0 + (w * 2 + 0) * 16 + l15, HW - 1);
    const int apx1 = min(px0 + (w * 2 + 1) * 16 + l15, HW - 1);
    const unsigned short* fhp = fh + (size_t)b * CG * HW * 8;
    const unsigned short* flp = fl + (size_t)b * CG * HW * 8;
    const unsigned short* gbh = gwh + (size_t)bq * CG * 128 * 8;
    const unsigned short* gbl = gwl + (size_t)bq * CG * 128 * 8;

    for (int ks = 0; ks < CG / 4; ++ks) {
        // A fragments (issued first, overlap with staging)
        const size_t arow = (size_t)(ks * 4 + l4) * HW;
        const bf16x8 Ahi0 = *(const bf16x8*)(fhp + (arow + apx0) * 8);
        const bf16x8 Alo0 = *(const bf16x8*)(flp + (arow + apx0) * 8);
        const bf16x8 Ahi1 = *(const bf16x8*)(fhp + (arow + apx1) * 8);
        const bf16x8 Alo1 = *(const bf16x8*)(flp + (arow + apx1) * 8);

        // stage B slab: hi at sB[0..4095], lo at sB[4096..8191] (ushorts)
        {
            const uint4* srcH = (const uint4*)(gbh + (size_t)ks * 4096);
            const uint4* srcL = (const uint4*)(gbl + (size_t)ks * 4096);
            uint4* dst = (uint4*)sB;
            dst[tid]       = srcH[tid];           // 512 uint4 = 4096 ush
            dst[512 + tid] = srcL[tid];
        }
        __syncthreads();

        const int bofs = (l4 * 128 + l15) * 8;
        #pragma unroll
        for (int jt = 0; jt < 8; ++jt) {
            const bf16x8 Bhi = *(const bf16x8*)(sB + bofs + jt * 128);
            const bf16x8 Blo = *(const bf16x8*)(sB + 4096 + bofs + jt * 128);
            acc[0][jt] = __builtin_amdgcn_mfma_f32_16x16x32_bf16(Alo0, Bhi, acc[0][jt], 0, 0, 0);
            acc[0][jt] = __builtin_amdgcn_mfma_f32_16x16x32_bf16(Ahi0, Blo, acc[0][jt], 0, 0, 0);
            acc[0][jt] = __builtin_amdgcn_mfma_f32_16x16x32_bf16(Ahi0, Bhi, acc[0][jt], 0, 0, 0);
            acc[1][jt] = __builtin_amdgcn_mfma_f32_16x16x32_bf16(Alo1, Bhi, acc[1][jt], 0, 0, 0);
            acc[1][jt] = __builtin_amdgcn_mfma_f32_16x16x32_bf16(Ahi1, Blo, acc[1][jt], 0, 0, 0);
            acc[1][jt] = __builtin_amdgcn_mfma_f32_16x16x32_bf16(Ahi1, Bhi, acc[1][jt], 0, 0, 0);
        }
        __syncthreads();                          // protect slab before next overwrite
    }

    // epilogue: gelu, attn logit (reduce over j), sigmoid
    const float fb0 = finb[0];
    #pragma unroll
    for (int p = 0; p < 2; ++p) {
        float pl[4] = {0.f, 0.f, 0.f, 0.f};
        #pragma unroll
        for (int jt = 0; jt < 8; ++jt) {
            float fw = finw[jt * 16 + l15];
            #pragma unroll
            for (int r = 0; r < 4; ++r)
                pl[r] = fmaf(gelu_exact(acc[p][jt][r]), fw, pl[r]);
        }
        #pragma unroll
        for (int r = 0; r < 4; ++r) {
            pl[r] += __shfl_xor(pl[r], 1);
            pl[r] += __shfl_xor(pl[r], 2);
            pl[r] += __shfl_xor(pl[r], 4);
            pl[r] += __shfl_xor(pl[r], 8);
        }
        if (l15 == 0) {
            #pragma unroll
            for (int r = 0; r < 4; ++r) {
                int lpx = (w * 2 + p) * 16 + l4 * 4 + r;
                int px  = px0 + lpx;
                float a = (px < HW) ? 1.0f / (1.0f + expf(-(pl[r] + fb0))) : 0.0f;
                sAttn[lpx] = a;
                if (WRITE_ATTN && px < HW) attn_out[bq * HW + px] = a;
            }
        }
    }
    __syncthreads();

    // S_a: waves 0-3 reduce sAttn[256]
    if (tid < 256) {
        float sa = sAttn[tid];
        #pragma unroll
        for (int d = 1; d < 64; d <<= 1) sa += __shfl_xor(sa, d);
        if (lane == 0) atomicAdd(&Sout[bq * (C + 1) + C], sa);
    }

    // S_fc[c]: coalesced column loads over 256 px, wave shfl-reduce per channel
    constexpr int CPW = C / 8;
    #pragma unroll 1
    for (int ci = 0; ci < CPW; ++ci) {
        const int c2 = w * CPW + ci;
        const float* fr = fbase + (size_t)c2 * HW;
        float s = 0.f;
        #pragma unroll
        for (int k = 0; k < 4; ++k) {
            int lpx = lane + 64 * k;
            int gc = min(px0 + lpx, HW - 1);
            s = fmaf(fr[gc], sAttn[lpx], s);      // sAttn==0 masks pad
        }
        #pragma unroll
        for (int d = 1; d < 64; d <<= 1) s += __shfl_xor(s, d);
        if (lane == 0) atomicAdd(&Sout[bq * (C + 1) + c2], s);
    }
}

__global__ __launch_bounds__(512)
void pool_fused(const float* __restrict__ feat0, const float* __restrict__ feat1,
                const float* __restrict__ feat2,
                const unsigned short* __restrict__ f0h, const unsigned short* __restrict__ f0l,
                const unsigned short* __restrict__ f1h, const unsigned short* __restrict__ f1l,
                const unsigned short* __restrict__ f2h, const unsigned short* __restrict__ f2l,
                const unsigned short* __restrict__ g0h, const unsigned short* __restrict__ g0l,
                const unsigned short* __restrict__ g1h, const unsigned short* __restrict__ g1l,
                const unsigned short* __restrict__ g2h, const unsigned short* __restrict__ g2l,
                const float* __restrict__ b20, const float* __restrict__ b21,
                const float* __restrict__ b22,
                const float* __restrict__ finw0, const float* __restrict__ finb0,
                const float* __restrict__ finw1, const float* __restrict__ finb1,
                const float* __restrict__ finw2, const float* __restrict__ finb2,
                float* __restrict__ S0, float* __restrict__ S1, float* __restrict__ S2,
                float* __restrict__ attn2)
{
    __shared__ __align__(16) unsigned short sB[8192];   // 16 KB slab (hi|lo)
    __shared__ float sAttn[256];
    const int blk = blockIdx.x;
    if (blk < 128) {                                 // scale 2 first (most K-steps)
        int bq = blk >> 1, t = blk & 1;              // 2 tiles of 256 (400 -> pad)
        pool_body<256, true>(feat2, 400, f2h, f2l, g2h, g2l, b22, finw2, finb2,
                             S2, attn2, bq, t, sB, sAttn);
    } else if (blk < 576) {
        int bb = blk - 128; int bq = bb / 7, t = bb % 7;     // 7 tiles (1600 -> pad)
        pool_body<128, false>(feat1, 1600, f1h, f1l, g1h, g1l, b21, finw1, finb1,
                              S1, nullptr, bq, t, sB, sAttn);
    } else {
        int bb = blk - 576; int bq = bb / 25, t = bb % 25;   // 25 tiles (6400)
        pool_body<64, false>(feat0, 6400, f0h, f0l, g0h, g0l, b20, finw0, finb0,
                             S0, nullptr, bq, t, sB, sAttn);
    }
}

// ---------------------------------------------------------------------------
// MLP layer 1 (unchanged)
// ---------------------------------------------------------------------------
__global__ __launch_bounds__(256)
void mlp1_kernel(const float* __restrict__ S0, const float* __restrict__ S1,
                 const float* __restrict__ S2,
                 const float* __restrict__ gb0, const float* __restrict__ gb1,
                 const float* __restrict__ gb2,
                 const float* __restrict__ attn2,
                 const float* __restrict__ w1, const float* __restrict__ b1,
                 float* __restrict__ X1)
{
    __shared__ float sCat[848];
    __shared__ float sP[256];
    const int tid = threadIdx.x, bq = blockIdx.x;

    for (int i = tid; i < 448; i += 256) {
        int sc, c;
        if (i < 64)       { sc = 0; c = i; }
        else if (i < 192) { sc = 1; c = i - 64; }
        else              { sc = 2; c = i - 192; }
        const int C = 64 << sc;
        const float* So = (sc == 0) ? S0 : (sc == 1) ? S1 : S2;
        const float* g  = (sc == 0) ? gb0 : (sc == 1) ? gb1 : gb2;
        float Sa = So[bq * (C + 1) + C];
        float Sf = So[bq * (C + 1) + c];
        float gamma = g[bq * 2 * C + c];
        float beta  = g[bq * 2 * C + C + c];
        sCat[i] = (gamma * Sf + beta * Sa) / (Sa + EPS);
    }
    for (int i = tid; i < 400; i += 256) sCat[448 + i] = attn2[bq * 400 + i];
    __syncthreads();

    const int o = blockIdx.y * 128 + (tid & 127), half = tid >> 7;
    const int k0 = half * 424;
    float a0 = 0.f, a1 = 0.f;
    #pragma unroll 2
    for (int k = 0; k < 424; k += 2) {
        a0 = fmaf(sCat[k0 + k],     w1[(k0 + k) * 512 + o],     a0);
        a1 = fmaf(sCat[k0 + k + 1], w1[(k0 + k + 1) * 512 + o], a1);
    }
    sP[tid] = a0 + a1;
    __syncthreads();
    if (tid < 128) {
        int oo = blockIdx.y * 128 + tid;
        X1[bq * 512 + oo] = sP[tid] + sP[tid + 128] + b1[oo];
    }
}

// ---------------------------------------------------------------------------
// MLP layers 2+3 (unchanged)
// ---------------------------------------------------------------------------
__global__ __launch_bounds__(256)
void mlp23_kernel(const float* __restrict__ X1,
                  const float* __restrict__ w2, const float* __restrict__ b2,
                  const float* __restrict__ w3, const float* __restrict__ b3,
                  float* __restrict__ out)
{
    __shared__ float sX1[512];
    __shared__ float sX2[256];
    __shared__ float sR[4];
    const int tid = threadIdx.x, bq = blockIdx.x;
    for (int i = tid; i < 512; i += 256) sX1[i] = gelu_exact(X1[bq * 512 + i]);
    __syncthreads();
    float a0 = b2[tid], a1 = 0.f, a2 = 0.f, a3 = 0.f;
    #pragma unroll 4
    for (int k = 0; k < 512; k += 4) {
        a0 = fmaf(sX1[k],     w2[(k)     * 256 + tid], a0);
        a1 = fmaf(sX1[k + 1], w2[(k + 1) * 256 + tid], a1);
        a2 = fmaf(sX1[k + 2], w2[(k + 2) * 256 + tid], a2);
        a3 = fmaf(sX1[k + 3], w2[(k + 3) * 256 + tid], a3);
    }
    sX2[tid] = gelu_exact((a0 + a1) + (a2 + a3));
    __syncthreads();
    float p = sX2[tid] * w3[tid];
    #pragma unroll
    for (int d = 1; d < 64; d <<= 1) p += __shfl_xor(p, d);
    if ((tid & 63) == 0) sR[tid >> 6] = p;
    __syncthreads();
    if (tid == 0) out[bq] = sR[0] + sR[1] + sR[2] + sR[3] + b3[0];
}

// ---------------------------------------------------------------------------
extern "C" void kernel_launch(void* const* d_in, const int* in_sizes, int n_in,
                              void* d_out, int out_size, void* d_ws, size_t ws_size,
                              hipStream_t stream)
{
    const float* feat0 = (const float*)d_in[0];
    const float* feat1 = (const float*)d_in[1];
    const float* feat2 = (const float*)d_in[2];
    const float* qe    = (const float*)d_in[3];
    const float* film_w0 = (const float*)d_in[4];
    const float* film_b0 = (const float*)d_in[5];
    const float* hid_w0  = (const float*)d_in[6];
    const float* hid_b0  = (const float*)d_in[7];
    const float* fin_w0  = (const float*)d_in[8];
    const float* fin_b0  = (const float*)d_in[9];
    const float* film_w1 = (const float*)d_in[10];
    const float* film_b1 = (const float*)d_in[11];
    const float* hid_w1  = (const float*)d_in[12];
    const float* hid_b1  = (const float*)d_in[13];
    const float* fin_w1  = (const float*)d_in[14];
    const float* fin_b1  = (const float*)d_in[15];
    const float* film_w2 = (const float*)d_in[16];
    const float* film_b2 = (const float*)d_in[17];
    const float* hid_w2  = (const float*)d_in[18];
    const float* hid_b2  = (const float*)d_in[19];
    const float* fin_w2  = (const float*)d_in[20];
    const float* fin_b2  = (const float*)d_in[21];
    const float* mlp_w1  = (const float*)d_in[22];
    const float* mlp_b1  = (const float*)d_in[23];
    const float* mlp_w2  = (const float*)d_in[24];
    const float* mlp_b2  = (const float*)d_in[25];
    const float* mlp_w3  = (const float*)d_in[26];
    const float* mlp_b3  = (const float*)d_in[27];

    float* ws = (float*)d_ws;
    float* S0    = ws;              // [64][65]
    float* S1    = ws + 4160;       // [64][129]
    float* S2    = ws + 12416;      // [64][257]   (Sout end 28864)
    float* gb0   = ws + 28864;      // [64][128]
    float* gb1   = ws + 37056;      // [64][256]
    float* gb2   = ws + 53440;      // [64][512]
    float* b20   = ws + 86208;      // [64][128]
    float* b21   = ws + 94400;
    float* b22   = ws + 102592;
    float* attn2 = ws + 110784;     // [64][400]
    float* X1    = ws + 136384;     // [64][512]   (end 169152 floats)

    // packed bf16 planes (ushort units) after the float region
    unsigned short* us = (unsigned short*)(ws + 169216);  // 16B-aligned
    unsigned short* f0h = us;                   // 2*64*6400   = 819200
    unsigned short* f0l = f0h + 819200;
    unsigned short* f1h = f0l + 819200;         // 2*128*1600  = 409600
    unsigned short* f1l = f1h + 409600;
    unsigned short* f2h = f1l + 409600;         // 2*256*400   = 204800
    unsigned short* f2l = f2h + 204800;
    unsigned short* g0h = f2l + 204800;         // 64*64*128   = 524288
    unsigned short* g0l = g0h + 524288;
    unsigned short* g1h = g0l + 524288;         // 64*128*128  = 1048576
    unsigned short* g1l = g1h + 1048576;
    unsigned short* g2h = g1l + 1048576;        // 64*256*128  = 2097152
    unsigned short* g2l = g2h + 2097152;        // end ≈ 21.5 MB

    hipMemsetAsync(d_ws, 0, 28864 * sizeof(float), stream);

    pack_feat_kernel<<<700, 256, 0, stream>>>(
        feat0, feat1, feat2, f0h, f0l, f1h, f1l, f2h, f2l);

    film2_kernel<<<dim3(BQ, 7), 256, 0, stream>>>(
        qe, film_w0, film_b0, film_w1, film_b1, film_w2, film_b2,
        gb0, gb1, gb2);

    pack_gw_kernel<<<1792, 256, 0, stream>>>(
        gb0, gb1, gb2, hid_w0, hid_w1, hid_w2,
        g0h, g0l, g1h, g1l, g2h, g2l);

    b2_kernel<<<dim3(BQ, 3), 256, 0, stream>>>(
        gb0, gb1, gb2,
        hid_w0, hid_b0, hid_w1, hid_b1, hid_w2, hid_b2,
        b20, b21, b22);

    pool_fused<<<2176, 512, 0, stream>>>(
        feat0, feat1, feat2,
        f0h, f0l, f1h, f1l, f2h, f2l,
        g0h, g0l, g1h, g1l, g2h, g2l,
        b20, b21, b22,
        fin_w0, fin_b0, fin_w1, fin_b1, fin_w2, fin_b2,
        S0, S1, S2, attn2);

    mlp1_kernel<<<dim3(BQ, 4), 256, 0, stream>>>(
        S0, S1, S2, gb0, gb1, gb2, attn2, mlp_w1, mlp_b1, X1);

    mlp23_kernel<<<BQ, 256, 0, stream>>>(
        X1, mlp_w2, mlp_b2, mlp_w3, mlp_b3, (float*)d_out);
}

// Round 12
// 233.792 us; speedup vs baseline: 1.9243x; 1.1037x over previous
//
#include <hip/hip_runtime.h>
#include <math.h>

#define BQ 64
#define HH 128
#define EPS 1e-8f

typedef short bf16x8 __attribute__((ext_vector_type(8)));
typedef float f32x4  __attribute__((ext_vector_type(4)));

__device__ __forceinline__ float gelu_exact(float x) {
    return 0.5f * x * (1.0f + erff(x * 0.70710678118654752440f));
}

__device__ __forceinline__ unsigned bf16_rne(float x) {
    unsigned u = __float_as_uint(x);
    return (u + 0x7FFFu + ((u >> 16) & 1u)) >> 16;
}
__device__ __forceinline__ uint2 split_pack(float a, float b) {
    unsigned ha = bf16_rne(a);
    float fa = __uint_as_float(ha << 16);
    unsigned la = bf16_rne(a - fa);
    unsigned hb = bf16_rne(b);
    float fb = __uint_as_float(hb << 16);
    unsigned lb = bf16_rne(b - fb);
    uint2 r; r.x = ha | (hb << 16); r.y = la | (lb << 16);
    return r;
}

// ---------------------------------------------------------------------------
// fused prep 1: pack_feat (blocks 0..699) + film2 (blocks 700..1147)
// ---------------------------------------------------------------------------
__device__ __forceinline__
void pack_feat_body(int i,
                    const float* __restrict__ f0, const float* __restrict__ f1,
                    const float* __restrict__ f2,
                    unsigned short* __restrict__ p0h, unsigned short* __restrict__ p0l,
                    unsigned short* __restrict__ p1h, unsigned short* __restrict__ p1l,
                    unsigned short* __restrict__ p2h, unsigned short* __restrict__ p2l)
{
    const float* f; unsigned short *oh, *ol; int HW; int idx;
    if (i < 102400)      { f = f0; oh = p0h; ol = p0l; HW = 6400; idx = i; }
    else if (i < 153600) { f = f1; oh = p1h; ol = p1l; HW = 1600; idx = i - 102400; }
    else if (i < 179200) { f = f2; oh = p2h; ol = p2l; HW = 400;  idx = i - 153600; }
    else return;
    const int px = idx % HW;
    const int cgb = idx / HW;
    const float* src = f + ((size_t)cgb * 8) * HW + px;
    float a[8];
    #pragma unroll
    for (int k = 0; k < 8; ++k) a[k] = src[(size_t)k * HW];
    unsigned hwd[4], lwd[4];
    #pragma unroll
    for (int k = 0; k < 4; ++k) {
        uint2 p = split_pack(a[2 * k], a[2 * k + 1]);
        hwd[k] = p.x; lwd[k] = p.y;
    }
    *(uint4*)&oh[(size_t)idx * 8] = make_uint4(hwd[0], hwd[1], hwd[2], hwd[3]);
    *(uint4*)&ol[(size_t)idx * 8] = make_uint4(lwd[0], lwd[1], lwd[2], lwd[3]);
}

__global__ __launch_bounds__(256)
void prep1_kernel(const float* __restrict__ f0, const float* __restrict__ f1,
                  const float* __restrict__ f2,
                  unsigned short* __restrict__ p0h, unsigned short* __restrict__ p0l,
                  unsigned short* __restrict__ p1h, unsigned short* __restrict__ p1l,
                  unsigned short* __restrict__ p2h, unsigned short* __restrict__ p2l,
                  const float* __restrict__ qe,
                  const float* __restrict__ fw0, const float* __restrict__ fb0,
                  const float* __restrict__ fw1, const float* __restrict__ fb1,
                  const float* __restrict__ fw2, const float* __restrict__ fb2,
                  float* __restrict__ gb0, float* __restrict__ gb1, float* __restrict__ gb2)
{
    const int tid = threadIdx.x;
    if (blockIdx.x < 700) {
        pack_feat_body(blockIdx.x * 256 + tid, f0, f1, f2, p0h, p0l, p1h, p1l, p2h, p2l);
        return;
    }
    // film2: bb in [0,448): chunk = bb/64, bq = bb%64
    __shared__ float sq[768];
    __shared__ float sP[256];
    const int bb = blockIdx.x - 700;
    const int chunk = bb >> 6, bq = bb & 63;
    int s, o0;
    if (chunk == 0)      { s = 0; o0 = 0; }
    else if (chunk <= 2) { s = 1; o0 = (chunk - 1) * 128; }
    else                 { s = 2; o0 = (chunk - 3) * 128; }
    const float* fw  = s == 0 ? fw0 : s == 1 ? fw1 : fw2;
    const float* fbv = s == 0 ? fb0 : s == 1 ? fb1 : fb2;
    float* gb        = s == 0 ? gb0 : s == 1 ? gb1 : gb2;
    const int twoC = 128 << s;

    for (int i = tid; i < 768; i += 256) sq[i] = qe[bq * 768 + i];
    __syncthreads();
    const int o = o0 + (tid & 127), half = tid >> 7;
    const int e0 = half * 384;
    float a0 = 0.f, a1 = 0.f;
    #pragma unroll 2
    for (int e = 0; e < 384; e += 2) {
        a0 = fmaf(sq[e0 + e],     fw[(e0 + e) * twoC + o],     a0);
        a1 = fmaf(sq[e0 + e + 1], fw[(e0 + e + 1) * twoC + o], a1);
    }
    sP[tid] = a0 + a1;
    __syncthreads();
    if (tid < 128) {
        int oo = o0 + tid;
        gb[bq * twoC + oo] = sP[tid] + sP[tid + 128] + fbv[oo];
    }
}

// ---------------------------------------------------------------------------
// fused prep 2: pack_gw (blocks 0..1791) + b2 (blocks 1792..1983)
// ---------------------------------------------------------------------------
__global__ __launch_bounds__(256)
void prep2_kernel(const float* __restrict__ gb0, const float* __restrict__ gb1,
                  const float* __restrict__ gb2,
                  const float* __restrict__ hw0_, const float* __restrict__ hb0,
                  const float* __restrict__ hw1_, const float* __restrict__ hb1,
                  const float* __restrict__ hw2_, const float* __restrict__ hb2,
                  unsigned short* __restrict__ g0h, unsigned short* __restrict__ g0l,
                  unsigned short* __restrict__ g1h, unsigned short* __restrict__ g1l,
                  unsigned short* __restrict__ g2h, unsigned short* __restrict__ g2l,
                  float* __restrict__ b20, float* __restrict__ b21, float* __restrict__ b22)
{
    const int tid = threadIdx.x;
    if (blockIdx.x < 1792) {
        int i = blockIdx.x * 256 + tid;
        const float *gb, *hw; unsigned short *oh, *ol; int C, idx;
        if (i < 65536)       { gb = gb0; hw = hw0_; oh = g0h; ol = g0l; C = 64;  idx = i; }
        else if (i < 196608) { gb = gb1; hw = hw1_; oh = g1h; ol = g1l; C = 128; idx = i - 65536; }
        else                 { gb = gb2; hw = hw2_; oh = g2h; ol = g2l; C = 256; idx = i - 196608; }
        const int j  = idx & 127;
        const int cg = (idx >> 7) % (C / 8);
        const int bq = idx / (128 * (C / 8));
        const int c0 = cg * 8;
        const float* g = gb + bq * 2 * C;
        float a[8];
        #pragma unroll
        for (int k = 0; k < 8; ++k) a[k] = g[c0 + k] * hw[(size_t)(c0 + k) * HH + j];
        unsigned hwd[4], lwd[4];
        #pragma unroll
        for (int k = 0; k < 4; ++k) {
            uint2 p = split_pack(a[2 * k], a[2 * k + 1]);
            hwd[k] = p.x; lwd[k] = p.y;
        }
        *(uint4*)&oh[(size_t)idx * 8] = make_uint4(hwd[0], hwd[1], hwd[2], hwd[3]);
        *(uint4*)&ol[(size_t)idx * 8] = make_uint4(lwd[0], lwd[1], lwd[2], lwd[3]);
        return;
    }
    // b2: bb in [0,192): s = bb/64, bq = bb%64
    __shared__ float sBeta[256];
    __shared__ float sP[256];
    const int bb = blockIdx.x - 1792;
    const int s = bb >> 6, bq = bb & 63;
    const float* gb = s == 0 ? gb0 : s == 1 ? gb1 : gb2;
    const float* hw = s == 0 ? hw0_ : s == 1 ? hw1_ : hw2_;
    const float* hb = s == 0 ? hb0 : s == 1 ? hb1 : hb2;
    float* b2       = s == 0 ? b20 : s == 1 ? b21 : b22;
    const int C = 64 << s;

    for (int i = tid; i < C; i += 256) sBeta[i] = gb[bq * 2 * C + C + i];
    __syncthreads();
    const int j = tid & 127, half = tid >> 7;
    const int c0 = half * (C / 2);
    float acc = 0.f;
    for (int c = 0; c < C / 2; ++c)
        acc = fmaf(sBeta[c0 + c], hw[(c0 + c) * HH + j], acc);
    sP[tid] = acc;
    __syncthreads();
    if (tid < 128) b2[bq * HH + tid] = hb[tid] + sP[tid] + sP[tid + 128];
}

// ---------------------------------------------------------------------------
// MFMA FiLM pool v4: QF=2 q-folding. Block = 8 waves (512 thr), 256-px tile,
// TWO q's per block (q-pair). Per ks: stage BOTH q B-slabs (32 KB LDS, one
// barrier pair), each wave computes 2 px-row-tiles x 8 jt x 2 q.
// acc = 32 f32x4 (AGPR side). A frags + S_fc feat reads amortized over 2 q.
// ---------------------------------------------------------------------------
#define MFMA3(ACC, ALO, AHI, BH, BL)                                            \
    ACC = __builtin_amdgcn_mfma_f32_16x16x32_bf16(ALO, BH, ACC, 0, 0, 0);       \
    ACC = __builtin_amdgcn_mfma_f32_16x16x32_bf16(AHI, BL, ACC, 0, 0, 0);       \
    ACC = __builtin_amdgcn_mfma_f32_16x16x32_bf16(AHI, BH, ACC, 0, 0, 0);

template<int C, bool WRITE_ATTN>
__device__ __forceinline__
void pool_body(const float* __restrict__ feat, int HW,
               const unsigned short* __restrict__ fh, const unsigned short* __restrict__ fl,
               const unsigned short* __restrict__ gwh, const unsigned short* __restrict__ gwl,
               const float* __restrict__ b2, const float* __restrict__ finw,
               const float* __restrict__ finb,
               float* __restrict__ Sout, float* __restrict__ attn_out,
               int b, int qp, int tile,
               unsigned short* sB, float* sAttn)
{
    const int tid  = threadIdx.x;
    const int w    = tid >> 6;
    const int lane = tid & 63;
    const int l15  = lane & 15, l4 = lane >> 4;
    const int px0  = tile * 256;
    constexpr int CG = C / 8;
    const int bq0 = b * 32 + qp * 2;
    const int bq1 = bq0 + 1;
    const float* fbase = feat + (size_t)b * C * HW;

    f32x4 accA[2][8], accB[2][8];            // [pt][jt] for q0 / q1
    #pragma unroll
    for (int jt = 0; jt < 8; ++jt) {
        float bv0 = b2[bq0 * HH + jt * 16 + l15];
        float bv1 = b2[bq1 * HH + jt * 16 + l15];
        accA[0][jt] = (f32x4){bv0, bv0, bv0, bv0};
        accA[1][jt] = (f32x4){bv0, bv0, bv0, bv0};
        accB[0][jt] = (f32x4){bv1, bv1, bv1, bv1};
        accB[1][jt] = (f32x4){bv1, bv1, bv1, bv1};
    }

    const int apx0 = min(px0 + (w * 2 + 0) * 16 + l15, HW - 1);
    const int apx1 = min(px0 + (w * 2 + 1) * 16 + l15, HW - 1);
    const unsigned short* fhp = fh + (size_t)b * CG * HW * 8;
    const unsigned short* flp = fl + (size_t)b * CG * HW * 8;
    const unsigned short* q0h = gwh + (size_t)bq0 * CG * 128 * 8;
    const unsigned short* q0l = gwl + (size_t)bq0 * CG * 128 * 8;
    const unsigned short* q1h = gwh + (size_t)bq1 * CG * 128 * 8;
    const unsigned short* q1l = gwl + (size_t)bq1 * CG * 128 * 8;

    for (int ks = 0; ks < CG / 4; ++ks) {
        const size_t arow = (size_t)(ks * 4 + l4) * HW;
        const bf16x8 Ahi0 = *(const bf16x8*)(fhp + (arow + apx0) * 8);
        const bf16x8 Alo0 = *(const bf16x8*)(flp + (arow + apx0) * 8);
        const bf16x8 Ahi1 = *(const bf16x8*)(fhp + (arow + apx1) * 8);
        const bf16x8 Alo1 = *(const bf16x8*)(flp + (arow + apx1) * 8);
        {
            uint4* dst = (uint4*)sB;
            dst[tid]        = ((const uint4*)(q0h + (size_t)ks * 4096))[tid];
            dst[512  + tid] = ((const uint4*)(q0l + (size_t)ks * 4096))[tid];
            dst[1024 + tid] = ((const uint4*)(q1h + (size_t)ks * 4096))[tid];
            dst[1536 + tid] = ((const uint4*)(q1l + (size_t)ks * 4096))[tid];
        }
        __syncthreads();
        const int bofs = (l4 * 128 + l15) * 8;
        #pragma unroll
        for (int jt = 0; jt < 8; ++jt) {
            const bf16x8 B0h = *(const bf16x8*)(sB + bofs + jt * 128);
            const bf16x8 B0l = *(const bf16x8*)(sB + 4096 + bofs + jt * 128);
            MFMA3(accA[0][jt], Alo0, Ahi0, B0h, B0l)
            MFMA3(accA[1][jt], Alo1, Ahi1, B0h, B0l)
            const bf16x8 B1h = *(const bf16x8*)(sB + 8192 + bofs + jt * 128);
            const bf16x8 B1l = *(const bf16x8*)(sB + 12288 + bofs + jt * 128);
            MFMA3(accB[0][jt], Alo0, Ahi0, B1h, B1l)
            MFMA3(accB[1][jt], Alo1, Ahi1, B1h, B1l)
        }
        __syncthreads();
    }

    // epilogue: gelu -> attn logit -> sigmoid, for both q's
    const float fb0 = finb[0];
    #pragma unroll
    for (int pt = 0; pt < 2; ++pt) {
        float p0[4] = {0.f, 0.f, 0.f, 0.f};
        float p1[4] = {0.f, 0.f, 0.f, 0.f};
        #pragma unroll
        for (int jt = 0; jt < 8; ++jt) {
            float fwv = finw[jt * 16 + l15];
            #pragma unroll
            for (int r = 0; r < 4; ++r) {
                p0[r] = fmaf(gelu_exact(accA[pt][jt][r]), fwv, p0[r]);
                p1[r] = fmaf(gelu_exact(accB[pt][jt][r]), fwv, p1[r]);
            }
        }
        #pragma unroll
        for (int r = 0; r < 4; ++r) {
            p0[r] += __shfl_xor(p0[r], 1);  p1[r] += __shfl_xor(p1[r], 1);
            p0[r] += __shfl_xor(p0[r], 2);  p1[r] += __shfl_xor(p1[r], 2);
            p0[r] += __shfl_xor(p0[r], 4);  p1[r] += __shfl_xor(p1[r], 4);
            p0[r] += __shfl_xor(p0[r], 8);  p1[r] += __shfl_xor(p1[r], 8);
        }
        if (l15 == 0) {
            #pragma unroll
            for (int r = 0; r < 4; ++r) {
                int lpx = (w * 2 + pt) * 16 + l4 * 4 + r;
                int px  = px0 + lpx;
                float a0v = (px < HW) ? 1.0f / (1.0f + expf(-(p0[r] + fb0))) : 0.0f;
                float a1v = (px < HW) ? 1.0f / (1.0f + expf(-(p1[r] + fb0))) : 0.0f;
                sAttn[lpx]       = a0v;
                sAttn[256 + lpx] = a1v;
                if (WRITE_ATTN && px < HW) {
                    attn_out[bq0 * HW + px] = a0v;
                    attn_out[bq1 * HW + px] = a1v;
                }
            }
        }
    }
    __syncthreads();

    // S_a for both q's (threads 0-255 -> q0, 256-511 -> q1)
    {
        float sa = sAttn[tid];
        #pragma unroll
        for (int d = 1; d < 64; d <<= 1) sa += __shfl_xor(sa, d);
        if (lane == 0) {
            int bqx = (tid < 256) ? bq0 : bq1;
            atomicAdd(&Sout[bqx * (C + 1) + C], sa);
        }
    }

    // S_fc[c]: one coalesced feat read serves both q's
    constexpr int CPW = C / 8;
    #pragma unroll 1
    for (int ci = 0; ci < CPW; ++ci) {
        const int c2 = w * CPW + ci;
        const float* fr = fbase + (size_t)c2 * HW;
        float s0 = 0.f, s1 = 0.f;
        #pragma unroll
        for (int k = 0; k < 4; ++k) {
            int lpx = lane + 64 * k;
            int gc = min(px0 + lpx, HW - 1);
            float fv = fr[gc];
            s0 = fmaf(fv, sAttn[lpx], s0);
            s1 = fmaf(fv, sAttn[256 + lpx], s1);
        }
        #pragma unroll
        for (int d = 1; d < 64; d <<= 1) {
            s0 += __shfl_xor(s0, d);
            s1 += __shfl_xor(s1, d);
        }
        if (lane == 0) {
            atomicAdd(&Sout[bq0 * (C + 1) + c2], s0);
            atomicAdd(&Sout[bq1 * (C + 1) + c2], s1);
        }
    }
}

__global__ __launch_bounds__(512)
void pool_fused(const unsigned short* __restrict__ f0h, const unsigned short* __restrict__ f0l,
                const unsigned short* __restrict__ f1h, const unsigned short* __restrict__ f1l,
                const unsigned short* __restrict__ f2h, const unsigned short* __restrict__ f2l,
                const unsigned short* __restrict__ g0h, const unsigned short* __restrict__ g0l,
                const unsigned short* __restrict__ g1h, const unsigned short* __restrict__ g1l,
                const unsigned short* __restrict__ g2h, const unsigned short* __restrict__ g2l,
                const float* __restrict__ feat0, const float* __restrict__ feat1,
                const float* __restrict__ feat2,
                const float* __restrict__ b20, const float* __restrict__ b21,
                const float* __restrict__ b22,
                const float* __restrict__ finw0, const float* __restrict__ finb0,
                const float* __restrict__ finw1, const float* __restrict__ finb1,
                const float* __restrict__ finw2, const float* __restrict__ finb2,
                float* __restrict__ S0, float* __restrict__ S1, float* __restrict__ S2,
                float* __restrict__ attn2)
{
    __shared__ __align__(16) unsigned short sB[16384];   // 32 KB: 2 q x (hi|lo) slabs
    __shared__ float sAttn[512];
    const int blk = blockIdx.x;
    // ordering: 16 qp-blocks sharing one A-tile are consecutive (L2 locality)
    if (blk < 64) {                       // scale 2: 2b x 2t x 16qp
        int bt = blk >> 4, qp = blk & 15;
        int b = bt >> 1, t = bt & 1;
        pool_body<256, true>(feat2, 400, f2h, f2l, g2h, g2l, b22, finw2, finb2,
                             S2, attn2, b, qp, t, sB, sAttn);
    } else if (blk < 288) {               // scale 1: 2b x 7t x 16qp
        int bb = blk - 64; int bt = bb >> 4, qp = bb & 15;
        int b = bt / 7, t = bt % 7;
        pool_body<128, false>(feat1, 1600, f1h, f1l, g1h, g1l, b21, finw1, finb1,
                              S1, nullptr, b, qp, t, sB, sAttn);
    } else {                              // scale 0: 2b x 25t x 16qp
        int bb = blk - 288; int bt = bb >> 4, qp = bb & 15;
        int b = bt / 25, t = bt % 25;
        pool_body<64, false>(feat0, 6400, f0h, f0l, g0h, g0l, b20, finw0, finb0,
                             S0, nullptr, b, qp, t, sB, sAttn);
    }
}

// ---------------------------------------------------------------------------
// MLP layer 1 (unchanged)
// ---------------------------------------------------------------------------
__global__ __launch_bounds__(256)
void mlp1_kernel(const float* __restrict__ S0, const float* __restrict__ S1,
                 const float* __restrict__ S2,
                 const float* __restrict__ gb0, const float* __restrict__ gb1,
                 const float* __restrict__ gb2,
                 const float* __restrict__ attn2,
                 const float* __restrict__ w1, const float* __restrict__ b1,
                 float* __restrict__ X1)
{
    __shared__ float sCat[848];
    __shared__ float sP[256];
    const int tid = threadIdx.x, bq = blockIdx.x;

    for (int i = tid; i < 448; i += 256) {
        int sc, c;
        if (i < 64)       { sc = 0; c = i; }
        else if (i < 192) { sc = 1; c = i - 64; }
        else              { sc = 2; c = i - 192; }
        const int C = 64 << sc;
        const float* So = (sc == 0) ? S0 : (sc == 1) ? S1 : S2;
        const float* g  = (sc == 0) ? gb0 : (sc == 1) ? gb1 : gb2;
        float Sa = So[bq * (C + 1) + C];
        float Sf = So[bq * (C + 1) + c];
        float gamma = g[bq * 2 * C + c];
        float beta  = g[bq * 2 * C + C + c];
        sCat[i] = (gamma * Sf + beta * Sa) / (Sa + EPS);
    }
    for (int i = tid; i < 400; i += 256) sCat[448 + i] = attn2[bq * 400 + i];
    __syncthreads();

    const int o = blockIdx.y * 128 + (tid & 127), half = tid >> 7;
    const int k0 = half * 424;
    float a0 = 0.f, a1 = 0.f;
    #pragma unroll 2
    for (int k = 0; k < 424; k += 2) {
        a0 = fmaf(sCat[k0 + k],     w1[(k0 + k) * 512 + o],     a0);
        a1 = fmaf(sCat[k0 + k + 1], w1[(k0 + k + 1) * 512 + o], a1);
    }
    sP[tid] = a0 + a1;
    __syncthreads();
    if (tid < 128) {
        int oo = blockIdx.y * 128 + tid;
        X1[bq * 512 + oo] = sP[tid] + sP[tid + 128] + b1[oo];
    }
}

// ---------------------------------------------------------------------------
// MLP layers 2+3 (unchanged)
// ---------------------------------------------------------------------------
__global__ __launch_bounds__(256)
void mlp23_kernel(const float* __restrict__ X1,
                  const float* __restrict__ w2, const float* __restrict__ b2,
                  const float* __restrict__ w3, const float* __restrict__ b3,
                  float* __restrict__ out)
{
    __shared__ float sX1[512];
    __shared__ float sX2[256];
    __shared__ float sR[4];
    const int tid = threadIdx.x, bq = blockIdx.x;
    for (int i = tid; i < 512; i += 256) sX1[i] = gelu_exact(X1[bq * 512 + i]);
    __syncthreads();
    float a0 = b2[tid], a1 = 0.f, a2 = 0.f, a3 = 0.f;
    #pragma unroll 4
    for (int k = 0; k < 512; k += 4) {
        a0 = fmaf(sX1[k],     w2[(k)     * 256 + tid], a0);
        a1 = fmaf(sX1[k + 1], w2[(k + 1) * 256 + tid], a1);
        a2 = fmaf(sX1[k + 2], w2[(k + 2) * 256 + tid], a2);
        a3 = fmaf(sX1[k + 3], w2[(k + 3) * 256 + tid], a3);
    }
    sX2[tid] = gelu_exact((a0 + a1) + (a2 + a3));
    __syncthreads();
    float p = sX2[tid] * w3[tid];
    #pragma unroll
    for (int d = 1; d < 64; d <<= 1) p += __shfl_xor(p, d);
    if ((tid & 63) == 0) sR[tid >> 6] = p;
    __syncthreads();
    if (tid == 0) out[bq] = sR[0] + sR[1] + sR[2] + sR[3] + b3[0];
}

// ---------------------------------------------------------------------------
extern "C" void kernel_launch(void* const* d_in, const int* in_sizes, int n_in,
                              void* d_out, int out_size, void* d_ws, size_t ws_size,
                              hipStream_t stream)
{
    const float* feat0 = (const float*)d_in[0];
    const float* feat1 = (const float*)d_in[1];
    const float* feat2 = (const float*)d_in[2];
    const float* qe    = (const float*)d_in[3];
    const float* film_w0 = (const float*)d_in[4];
    const float* film_b0 = (const float*)d_in[5];
    const float* hid_w0  = (const float*)d_in[6];
    const float* hid_b0  = (const float*)d_in[7];
    const float* fin_w0  = (const float*)d_in[8];
    const float* fin_b0  = (const float*)d_in[9];
    const float* film_w1 = (const float*)d_in[10];
    const float* film_b1 = (const float*)d_in[11];
    const float* hid_w1  = (const float*)d_in[12];
    const float* hid_b1  = (const float*)d_in[13];
    const float* fin_w1  = (const float*)d_in[14];
    const float* fin_b1  = (const float*)d_in[15];
    const float* film_w2 = (const float*)d_in[16];
    const float* film_b2 = (const float*)d_in[17];
    const float* hid_w2  = (const float*)d_in[18];
    const float* hid_b2  = (const float*)d_in[19];
    const float* fin_w2  = (const float*)d_in[20];
    const float* fin_b2  = (const float*)d_in[21];
    const float* mlp_w1  = (const float*)d_in[22];
    const float* mlp_b1  = (const float*)d_in[23];
    const float* mlp_w2  = (const float*)d_in[24];
    const float* mlp_b2  = (const float*)d_in[25];
    const float* mlp_w3  = (const float*)d_in[26];
    const float* mlp_b3  = (const float*)d_in[27];

    float* ws = (float*)d_ws;
    float* S0    = ws;              // [64][65]
    float* S1    = ws + 4160;       // [64][129]
    float* S2    = ws + 12416;      // [64][257]   (Sout end 28864)
    float* gb0   = ws + 28864;      // [64][128]
    float* gb1   = ws + 37056;      // [64][256]
    float* gb2   = ws + 53440;      // [64][512]
    float* b20   = ws + 86208;      // [64][128]
    float* b21   = ws + 94400;
    float* b22   = ws + 102592;
    float* attn2 = ws + 110784;     // [64][400]
    float* X1    = ws + 136384;     // [64][512]   (end 169152 floats)

    unsigned short* us = (unsigned short*)(ws + 169216);  // 16B-aligned
    unsigned short* f0h = us;                   // 819200 each plane
    unsigned short* f0l = f0h + 819200;
    unsigned short* f1h = f0l + 819200;         // 409600
    unsigned short* f1l = f1h + 409600;
    unsigned short* f2h = f1l + 409600;         // 204800
    unsigned short* f2l = f2h + 204800;
    unsigned short* g0h = f2l + 204800;         // 524288
    unsigned short* g0l = g0h + 524288;
    unsigned short* g1h = g0l + 524288;         // 1048576
    unsigned short* g1l = g1h + 1048576;
    unsigned short* g2h = g1l + 1048576;        // 2097152
    unsigned short* g2l = g2h + 2097152;

    hipMemsetAsync(d_ws, 0, 28864 * sizeof(float), stream);

    prep1_kernel<<<1148, 256, 0, stream>>>(
        feat0, feat1, feat2, f0h, f0l, f1h, f1l, f2h, f2l,
        qe, film_w0, film_b0, film_w1, film_b1, film_w2, film_b2,
        gb0, gb1, gb2);

    prep2_kernel<<<1984, 256, 0, stream>>>(
        gb0, gb1, gb2,
        hid_w0, hid_b0, hid_w1, hid_b1, hid_w2, hid_b2,
        g0h, g0l, g1h, g1l, g2h, g2l,
        b20, b21, b22);

    pool_fused<<<1088, 512, 0, stream>>>(
        f0h, f0l, f1h, f1l, f2h, f2l,
        g0h, g0l, g1h, g1l, g2h, g2l,
        feat0, feat1, feat2,
        b20, b21, b22,
        fin_w0, fin_b0, fin_w1, fin_b1, fin_w2, fin_b2,
        S0, S1, S2, attn2);

    mlp1_kernel<<<dim3(BQ, 4), 256, 0, stream>>>(
        S0, S1, S2, gb0, gb1, gb2, attn2, mlp_w1, mlp_b1, X1);

    mlp23_kernel<<<BQ, 256, 0, stream>>>(
        X1, mlp_w2, mlp_b2, mlp_w3, mlp_b3, (float*)d_out);
}